// Round 6
// baseline (3324.889 us; speedup 1.0000x reference)
//
#include <hip/hip_runtime.h>
#include <hip/hip_bf16.h>

// PCGTConvLayer round 6: identical verified pipeline (round-5 checks all
// passed at bf16 noise), but output written as FLOAT32 — the reference
// returns f32, and round-5's 2.117 error == exactly the max|err| statistic
// of a fully decorrelated same-distribution output (f32 buffer read of our
// bf16 writes). N=32768 IN=256 D=128 H=4 M=4 KP=128 S=256.

#define INV_SCALE 0.08838834764831845f

typedef __attribute__((ext_vector_type(8))) short bf16x8;
typedef __attribute__((ext_vector_type(4))) float floatx4;
typedef unsigned short ushort_t;
typedef unsigned int uint32;

// ---- ws layout (bytes) ----
#define OFF_Q    0ull
#define OFF_K    33554432ull
#define OFF_V    67108864ull
#define OFF_LOC  100663296ull
#define OFF_RPK  109051904ull
#define OFF_RPV  109576192ull
#define OFF_XC   110100480ull
#define OFF_WC   126877696ull
#define OFF_SCAL 127671296ull
#define OFF_FLAG 127671304ull

#define WC_WQ 0
#define WC_WK 131072
#define WC_WV 262144
#define WC_BQ 393216
#define WC_BK 393728
#define WC_BV 394240
#define WC_SEED 394752
#define WC_TOT 396800

static __device__ __forceinline__ float bflo(uint32 u) {
  return __uint_as_float(u << 16);
}
static __device__ __forceinline__ float bfhi(uint32 u) {
  return __uint_as_float(u & 0xffff0000u);
}
static __device__ __forceinline__ float bf2f(ushort_t u) {
  return __uint_as_float(((uint32)u) << 16);
}
static __device__ __forceinline__ ushort_t f2bf(float f) {
  uint32 x = __float_as_uint(f);
  uint32 r = x + 0x7fffu + ((x >> 16) & 1u);
  return (ushort_t)(r >> 16);
}
static __device__ __forceinline__ uint32 pack2bf(float a, float b) {
  return (uint32)f2bf(a) | ((uint32)f2bf(b) << 16);
}

// ---------------------------------------------------------------------------
// K0: dtype detection (robustness; inputs measured f32 on this harness).
// ---------------------------------------------------------------------------
__global__ __launch_bounds__(64) void k_detect(const uint32* __restrict__ xw,
                                               const ushort_t* __restrict__ betaRaw,
                                               uint32* __restrict__ flags) {
  const int lane = threadIdx.x;
  const uint32 w = xw[lane * 137 + 3];
  const int e = (w >> 7) & 0xff;
  const unsigned long long b = __ballot(e >= 100 && e <= 140);
  if (lane == 0) {
    flags[0] = (__popcll(b) >= 48) ? 1u : 0u;
    flags[1] = (betaRaw[0] != 0) ? 1u : 0u;
  }
}

// ---------------------------------------------------------------------------
// K1: canonicalize float inputs to bf16.
// ---------------------------------------------------------------------------
static __device__ __forceinline__ void conv8(const void* src, long j, int isB,
                                             ushort_t* dst) {
  if (isB) {
    *reinterpret_cast<uint4*>(dst) =
        *reinterpret_cast<const uint4*>(reinterpret_cast<const ushort_t*>(src) + j);
  } else {
    const float* f = reinterpret_cast<const float*>(src) + j;
    const float4 a = *reinterpret_cast<const float4*>(f);
    const float4 b = *reinterpret_cast<const float4*>(f + 4);
    uint4 o;
    o.x = pack2bf(a.x, a.y); o.y = pack2bf(a.z, a.w);
    o.z = pack2bf(b.x, b.y); o.w = pack2bf(b.z, b.w);
    *reinterpret_cast<uint4*>(dst) = o;
  }
}

__global__ __launch_bounds__(256) void k_convert(
    const void* __restrict__ x,
    const void* __restrict__ Wq, const void* __restrict__ bq,
    const void* __restrict__ Wk, const void* __restrict__ bk,
    const void* __restrict__ Wv, const void* __restrict__ bv,
    const void* __restrict__ seeds, const void* __restrict__ alpha,
    const void* __restrict__ beta,
    ushort_t* __restrict__ xc, ushort_t* __restrict__ wc,
    float* __restrict__ scal, const uint32* __restrict__ flags)
{
  const int isB = (int)flags[0];
  const long i8 = ((long)blockIdx.x * 256 + threadIdx.x) * 8;
  if (blockIdx.y == 0) {
    conv8(x, i8, isB, xc + i8);   // 8,388,608 elems == 4096 blocks exactly
  } else {
    if (i8 < WC_TOT) {
      const void* src; long j;
      if (i8 < WC_WK)        { src = Wq;    j = i8; }
      else if (i8 < WC_WV)   { src = Wk;    j = i8 - WC_WK; }
      else if (i8 < WC_BQ)   { src = Wv;    j = i8 - WC_WV; }
      else if (i8 < WC_BK)   { src = bq;    j = i8 - WC_BQ; }
      else if (i8 < WC_BV)   { src = bk;    j = i8 - WC_BK; }
      else if (i8 < WC_SEED) { src = bv;    j = i8 - WC_BV; }
      else                   { src = seeds; j = i8 - WC_SEED; }
      conv8(src, j, isB, wc + i8);
    }
    if (blockIdx.x == 0 && threadIdx.x == 0) {
      const int isBS = (int)flags[1];
      scal[0] = isBS ? bf2f(reinterpret_cast<const ushort_t*>(alpha)[0])
                     : reinterpret_cast<const float*>(alpha)[0];
      scal[1] = isBS ? bf2f(reinterpret_cast<const ushort_t*>(beta)[0])
                     : reinterpret_cast<const float*>(beta)[0];
    }
  }
}

// ---------------------------------------------------------------------------
// K2: QKV projection GEMM (bf16 MFMA 16x16x32), 64x64 tile, 2x2 waves.
// Verified by round-5 CHK1 at 65536 hashed points (max err 3.05e-5).
// ---------------------------------------------------------------------------
__global__ __launch_bounds__(256) void k_qkv(
    const ushort_t* __restrict__ xc, const ushort_t* __restrict__ wc,
    ushort_t* __restrict__ Qb, ushort_t* __restrict__ Kb, ushort_t* __restrict__ Vb)
{
  const int sel = blockIdx.z;
  const ushort_t* W    = wc + (sel == 0 ? WC_WQ : (sel == 1 ? WC_WK : WC_WV));
  const ushort_t* bias = wc + (sel == 0 ? WC_BQ : (sel == 1 ? WC_BK : WC_BV));
  ushort_t* out        = sel == 0 ? Qb : (sel == 1 ? Kb : Vb);

  const int mTile = blockIdx.y * 64;
  const int nTile = blockIdx.x * 64;
  const int tid = threadIdx.x;
  const int lane = tid & 63;
  const int wv = tid >> 6;
  const int waveM = wv >> 1, waveN = wv & 1;
  const int l16 = lane & 15, quad = lane >> 4;

  __shared__ __align__(16) ushort_t As[64 * 32];
  __shared__ __align__(16) ushort_t Bs[64 * 32];

  floatx4 acc[2][2] = {};

  const int ar = tid >> 2, ac = (tid & 3) * 8;
  const int bkk = tid >> 3, bj = (tid & 7) * 8;

  for (int k0 = 0; k0 < 256; k0 += 32) {
    uint4 av = *reinterpret_cast<const uint4*>(xc + (size_t)(mTile + ar) * 256 + k0 + ac);
    *reinterpret_cast<uint4*>(&As[ar * 32 + ac]) = av;

    uint4 bvv = *reinterpret_cast<const uint4*>(W + (size_t)(k0 + bkk) * 512 + nTile + bj);
    const ushort_t* bu = reinterpret_cast<const ushort_t*>(&bvv);
#pragma unroll
    for (int i = 0; i < 8; ++i) Bs[(bj + i) * 32 + bkk] = bu[i];
    __syncthreads();

    bf16x8 aF[2], bF[2];
#pragma unroll
    for (int mi = 0; mi < 2; ++mi)
      aF[mi] = *reinterpret_cast<const bf16x8*>(&As[(waveM * 32 + mi * 16 + l16) * 32 + quad * 8]);
#pragma unroll
    for (int ni = 0; ni < 2; ++ni)
      bF[ni] = *reinterpret_cast<const bf16x8*>(&Bs[(waveN * 32 + ni * 16 + l16) * 32 + quad * 8]);
#pragma unroll
    for (int mi = 0; mi < 2; ++mi)
#pragma unroll
      for (int ni = 0; ni < 2; ++ni)
        acc[mi][ni] = __builtin_amdgcn_mfma_f32_16x16x32_bf16(aF[mi], bF[ni], acc[mi][ni], 0, 0, 0);
    __syncthreads();
  }

#pragma unroll
  for (int mi = 0; mi < 2; ++mi) {
#pragma unroll
    for (int ni = 0; ni < 2; ++ni) {
      const int col = nTile + waveN * 32 + ni * 16 + l16;
      const float bf = bf2f(bias[col]);
#pragma unroll
      for (int r = 0; r < 4; ++r) {
        const int row = mTile + waveM * 32 + mi * 16 + quad * 4 + r;
        out[(size_t)row * 512 + col] = f2bf(acc[mi][ni][r] + bf);
      }
    }
  }
}

// ---------------------------------------------------------------------------
// K3: fused fine attention (verified by round-5 CHK2/CHK3).
// ---------------------------------------------------------------------------
__global__ __launch_bounds__(256) void k_fine(
    const ushort_t* __restrict__ Qb, const ushort_t* __restrict__ Kb,
    const ushort_t* __restrict__ Vb, const int* __restrict__ pidx_all,
    const ushort_t* __restrict__ wc,
    ushort_t* __restrict__ locS, ushort_t* __restrict__ rpk, ushort_t* __restrict__ rpv)
{
  const int k = blockIdx.x, pg = blockIdx.y;
  const int tid = threadIdx.x, lane = tid & 63, wv = tid >> 6;
  const int* pidx = pidx_all + k * 256;

  __shared__ __align__(16) ushort_t SB[128 * 256];
  const uint32* SBU = reinterpret_cast<const uint32*>(SB);

  float accA[16], accB[16];
  float P0[16], P1[16], P2[16], P3[16];
#pragma unroll
  for (int r = 0; r < 16; ++r) { accA[r] = 0.f; accB[r] = 0.f; }

  for (int h = 0; h < 4; ++h) {
#pragma unroll
    for (int i = 0; i < 16; ++i) {
      const int e8 = tid + 256 * i;
      const int q = e8 >> 4, dc = (e8 & 15) * 8;
      uint4 kv = *reinterpret_cast<const uint4*>(Kb + (size_t)pidx[q] * 512 + h * 128 + dc);
      const ushort_t* ku = reinterpret_cast<const ushort_t*>(&kv);
      const int qp = q >> 1, qb = q & 1;
#pragma unroll
      for (int j = 0; j < 8; ++j) {
        const int d = dc + j;
        SB[d * 256 + (((qp ^ (d & 31)) << 1) | qb)] = ku[j];
      }
    }
    __syncthreads();

#pragma unroll
    for (int r = 0; r < 16; ++r) {
      const int p = pg * 64 + wv * 16 + r;
      const uint32* qsrc = reinterpret_cast<const uint32*>(Qb + (size_t)pidx[p] * 512 + h * 128);
      float s00 = 0.f, s01 = 0.f, s10 = 0.f, s11 = 0.f;
#pragma unroll 8
      for (int dc = 0; dc < 64; ++dc) {
        const uint32 qv = qsrc[dc];
        const float q0 = bflo(qv), q1 = bfhi(qv);
        const int d0 = dc * 2, d1 = d0 + 1;
        const int c0 = lane ^ (d0 & 31);
        const int c1 = lane ^ (d1 & 31);
        const uint32 u00 = SBU[d0 * 128 + c0];
        const uint32 u01 = SBU[d0 * 128 + c0 + 64];
        const uint32 u10 = SBU[d1 * 128 + c1];
        const uint32 u11 = SBU[d1 * 128 + c1 + 64];
        s00 += q0 * bflo(u00) + q1 * bflo(u10);
        s01 += q0 * bfhi(u00) + q1 * bfhi(u10);
        s10 += q0 * bflo(u01) + q1 * bflo(u11);
        s11 += q0 * bfhi(u01) + q1 * bfhi(u11);
      }
      s00 *= INV_SCALE; s01 *= INV_SCALE; s10 *= INV_SCALE; s11 *= INV_SCALE;
      float mx = fmaxf(fmaxf(s00, s01), fmaxf(s10, s11));
#pragma unroll
      for (int off = 32; off >= 1; off >>= 1) mx = fmaxf(mx, __shfl_xor(mx, off));
      const float e00 = __expf(s00 - mx), e01 = __expf(s01 - mx);
      const float e10 = __expf(s10 - mx), e11 = __expf(s11 - mx);
      float sm = e00 + e01 + e10 + e11;
#pragma unroll
      for (int off = 32; off >= 1; off >>= 1) sm += __shfl_xor(sm, off);
      const float inv = 1.0f / sm;
      P0[r] = e00 * inv; P1[r] = e01 * inv; P2[r] = e10 * inv; P3[r] = e11 * inv;
    }

    float q00 = 0.f, q01 = 0.f, q10 = 0.f, q11 = 0.f;
    if (pg == h) {
      const uint32* ssrc = reinterpret_cast<const uint32*>(wc + WC_SEED + (size_t)(wv * 4 + h) * 128);
      float s00 = 0.f, s01 = 0.f, s10 = 0.f, s11 = 0.f;
#pragma unroll 8
      for (int dc = 0; dc < 64; ++dc) {
        const uint32 qv = ssrc[dc];
        const float a0 = bflo(qv), a1 = bfhi(qv);
        const int d0 = dc * 2, d1 = d0 + 1;
        const int c0 = lane ^ (d0 & 31);
        const int c1 = lane ^ (d1 & 31);
        const uint32 u00 = SBU[d0 * 128 + c0];
        const uint32 u01 = SBU[d0 * 128 + c0 + 64];
        const uint32 u10 = SBU[d1 * 128 + c1];
        const uint32 u11 = SBU[d1 * 128 + c1 + 64];
        s00 += a0 * bflo(u00) + a1 * bflo(u10);
        s01 += a0 * bfhi(u00) + a1 * bfhi(u10);
        s10 += a0 * bflo(u01) + a1 * bflo(u11);
        s11 += a0 * bfhi(u01) + a1 * bfhi(u11);
      }
      s00 *= INV_SCALE; s01 *= INV_SCALE; s10 *= INV_SCALE; s11 *= INV_SCALE;
      float mx = fmaxf(fmaxf(s00, s01), fmaxf(s10, s11));
#pragma unroll
      for (int off = 32; off >= 1; off >>= 1) mx = fmaxf(mx, __shfl_xor(mx, off));
      const float e00 = __expf(s00 - mx), e01 = __expf(s01 - mx);
      const float e10 = __expf(s10 - mx), e11 = __expf(s11 - mx);
      float sm = e00 + e01 + e10 + e11;
#pragma unroll
      for (int off = 32; off >= 1; off >>= 1) sm += __shfl_xor(sm, off);
      const float inv = 1.0f / sm;
      q00 = e00 * inv; q01 = e01 * inv; q10 = e10 * inv; q11 = e11 * inv;

      float rk0 = 0.f, rk1 = 0.f;
      const int d0 = 2 * lane, d1 = 2 * lane + 1;
#pragma unroll 4
      for (int qp = 0; qp < 64; ++qp) {
        const float pa = __shfl(q00, qp), pb = __shfl(q01, qp);
        const float pc = __shfl(q10, qp), pd = __shfl(q11, qp);
        const int c0 = qp ^ (d0 & 31);
        const int c1 = qp ^ (d1 & 31);
        const uint32 u0  = SBU[d0 * 128 + c0];
        const uint32 u0b = SBU[d0 * 128 + c0 + 64];
        const uint32 u1  = SBU[d1 * 128 + c1];
        const uint32 u1b = SBU[d1 * 128 + c1 + 64];
        rk0 += pa * bflo(u0) + pb * bfhi(u0) + pc * bflo(u0b) + pd * bfhi(u0b);
        rk1 += pa * bflo(u1) + pb * bfhi(u1) + pc * bflo(u1b) + pd * bfhi(u1b);
      }
      reinterpret_cast<uint32*>(rpk + ((size_t)((k * 4 + wv) * 4 + h)) * 128)[lane] = pack2bf(rk0, rk1);
    }
    __syncthreads();

#pragma unroll
    for (int i = 0; i < 16; ++i) {
      const int e8 = tid + 256 * i;
      const int q = e8 >> 4, dc = (e8 & 15) * 8;
      uint4 vv = *reinterpret_cast<const uint4*>(Vb + (size_t)pidx[q] * 512 + h * 128 + dc);
      *reinterpret_cast<uint4*>(&SB[q * 128 + dc]) = vv;
    }
    __syncthreads();

#pragma unroll
    for (int r = 0; r < 16; ++r) {
      float a0 = 0.f, a1 = 0.f;
#pragma unroll 4
      for (int qp = 0; qp < 64; ++qp) {
        const float pa = __shfl(P0[r], qp);
        const float pb = __shfl(P1[r], qp);
        const float pc = __shfl(P2[r], qp);
        const float pd = __shfl(P3[r], qp);
        const uint32 v00 = SBU[(2 * qp) * 64 + lane];
        const uint32 v01 = SBU[(2 * qp + 1) * 64 + lane];
        const uint32 v10 = SBU[(128 + 2 * qp) * 64 + lane];
        const uint32 v11 = SBU[(129 + 2 * qp) * 64 + lane];
        a0 += pa * bflo(v00) + pb * bflo(v01) + pc * bflo(v10) + pd * bflo(v11);
        a1 += pa * bfhi(v00) + pb * bfhi(v01) + pc * bfhi(v10) + pd * bfhi(v11);
      }
      accA[r] += a0; accB[r] += a1;
    }

    if (pg == h) {
      float rv0 = 0.f, rv1 = 0.f;
#pragma unroll 4
      for (int qp = 0; qp < 64; ++qp) {
        const float pa = __shfl(q00, qp), pb = __shfl(q01, qp);
        const float pc = __shfl(q10, qp), pd = __shfl(q11, qp);
        const uint32 v00 = SBU[(2 * qp) * 64 + lane];
        const uint32 v01 = SBU[(2 * qp + 1) * 64 + lane];
        const uint32 v10 = SBU[(128 + 2 * qp) * 64 + lane];
        const uint32 v11 = SBU[(129 + 2 * qp) * 64 + lane];
        rv0 += pa * bflo(v00) + pb * bflo(v01) + pc * bflo(v10) + pd * bflo(v11);
        rv1 += pa * bfhi(v00) + pb * bfhi(v01) + pc * bfhi(v10) + pd * bfhi(v11);
      }
      reinterpret_cast<uint32*>(rpv + ((size_t)((k * 4 + wv) * 4 + h)) * 128)[lane] = pack2bf(rv0, rv1);
    }
    __syncthreads();
  }

#pragma unroll
  for (int r = 0; r < 16; ++r) {
    const int p = pg * 64 + wv * 16 + r;
    const int n = pidx[p];
    reinterpret_cast<uint32*>(locS)[(size_t)n * 64 + lane] =
        pack2bf(accA[r] * 0.25f, accB[r] * 0.25f);
  }
}

// ---------------------------------------------------------------------------
// K4: global cross-attention + final combine -> FLOAT32 output [N,128].
// ---------------------------------------------------------------------------
__global__ __launch_bounds__(256) void k_cross(
    const ushort_t* __restrict__ Qb, const ushort_t* __restrict__ Vb,
    const ushort_t* __restrict__ rpk, const ushort_t* __restrict__ rpv,
    const ushort_t* __restrict__ locS, const float* __restrict__ scal,
    float* __restrict__ out)
{
  const int n0 = blockIdx.x * 16;
  const int tid = threadIdx.x, lane = tid & 63, wv = tid >> 6;

  __shared__ __align__(16) ushort_t RC[64 * 132];
  __shared__ __align__(16) float Qs[16 * 128];

  float g0[4] = {0.f, 0.f, 0.f, 0.f}, g1[4] = {0.f, 0.f, 0.f, 0.f};

  for (int h = 0; h < 4; ++h) {
    __syncthreads();
#pragma unroll
    for (int i = 0; i < 4; ++i) {
      const int e2 = tid + 256 * i;
      const int r = e2 >> 6, dp = e2 & 63;
      const uint32 v = *reinterpret_cast<const uint32*>(Qb + (size_t)(n0 + r) * 512 + h * 128 + 2 * dp);
      Qs[r * 128 + 2 * dp] = bflo(v);
      Qs[r * 128 + 2 * dp + 1] = bfhi(v);
    }

    float sc[4][8];
    for (int c = 0; c < 8; ++c) {
      __syncthreads();
#pragma unroll
      for (int i = 0; i < 4; ++i) {
        const int e8 = tid + 256 * i;
        const int r = e8 >> 4, dc = (e8 & 15) * 8;
        uint4 v = *reinterpret_cast<const uint4*>(rpk + ((size_t)((c * 64 + r) * 4 + h)) * 128 + dc);
        const ushort4* hv = reinterpret_cast<const ushort4*>(&v);
        *reinterpret_cast<ushort4*>(&RC[r * 132 + dc]) = hv[0];
        *reinterpret_cast<ushort4*>(&RC[r * 132 + dc + 4]) = hv[1];
      }
      __syncthreads();
      float acc[4] = {0.f, 0.f, 0.f, 0.f};
#pragma unroll 8
      for (int dc = 0; dc < 32; ++dc) {
        const ushort4 kv = *reinterpret_cast<const ushort4*>(&RC[lane * 132 + dc * 4]);
        const float k0 = bf2f(kv.x), k1 = bf2f(kv.y), k2 = bf2f(kv.z), k3 = bf2f(kv.w);
#pragma unroll
        for (int j = 0; j < 4; ++j) {
          const float4 qv = *reinterpret_cast<const float4*>(&Qs[(wv * 4 + j) * 128 + dc * 4]);
          acc[j] += qv.x * k0 + qv.y * k1 + qv.z * k2 + qv.w * k3;
        }
      }
#pragma unroll
      for (int j = 0; j < 4; ++j) sc[j][c] = acc[j] * INV_SCALE;
    }

#pragma unroll
    for (int j = 0; j < 4; ++j) {
      float mx = sc[j][0];
#pragma unroll
      for (int c = 1; c < 8; ++c) mx = fmaxf(mx, sc[j][c]);
#pragma unroll
      for (int off = 32; off >= 1; off >>= 1) mx = fmaxf(mx, __shfl_xor(mx, off));
      float s = 0.f;
#pragma unroll
      for (int c = 0; c < 8; ++c) { sc[j][c] = __expf(sc[j][c] - mx); s += sc[j][c]; }
#pragma unroll
      for (int off = 32; off >= 1; off >>= 1) s += __shfl_xor(s, off);
      const float inv = 1.0f / s;
#pragma unroll
      for (int c = 0; c < 8; ++c) sc[j][c] *= inv;
    }

    for (int c = 0; c < 8; ++c) {
      __syncthreads();
#pragma unroll
      for (int i = 0; i < 4; ++i) {
        const int e8 = tid + 256 * i;
        const int r = e8 >> 4, dc = (e8 & 15) * 8;
        uint4 v = *reinterpret_cast<const uint4*>(rpv + ((size_t)((c * 64 + r) * 4 + h)) * 128 + dc);
        const ushort4* hv = reinterpret_cast<const ushort4*>(&v);
        *reinterpret_cast<ushort4*>(&RC[r * 132 + dc]) = hv[0];
        *reinterpret_cast<ushort4*>(&RC[r * 132 + dc + 4]) = hv[1];
      }
      __syncthreads();
#pragma unroll 8
      for (int q = 0; q < 64; ++q) {
        const uint32 v = *reinterpret_cast<const uint32*>(&RC[q * 132 + 2 * lane]);
        const float f0 = bflo(v), f1 = bfhi(v);
#pragma unroll
        for (int j = 0; j < 4; ++j) {
          const float pj = __shfl(sc[j][c], q);
          g0[j] += pj * f0;
          g1[j] += pj * f1;
        }
      }
    }
  }

  const float alpha = 1.0f / (1.0f + __expf(-scal[0]));
  const float beta = scal[1];
#pragma unroll
  for (int j = 0; j < 4; ++j) {
    const int n = n0 + wv * 4 + j;
    const uint32 lv = reinterpret_cast<const uint32*>(locS)[(size_t)n * 64 + lane];
    float v0 = 0.f, v1 = 0.f;
#pragma unroll
    for (int hh = 0; hh < 4; ++hh) {
      const uint32 vv = *reinterpret_cast<const uint32*>(Vb + (size_t)n * 512 + hh * 128 + 2 * lane);
      v0 += bflo(vv); v1 += bfhi(vv);
    }
    const float r0 = alpha * bflo(lv) + (1.0f - alpha) * g0[j] * 0.25f + beta * v0 * 0.25f;
    const float r1 = alpha * bfhi(lv) + (1.0f - alpha) * g1[j] * 0.25f + beta * v1 * 0.25f;
    // FLOAT32 output: reference returns f32 -> d_out is float*
    reinterpret_cast<float2*>(out)[(size_t)n * 64 + lane] = make_float2(r0, r1);
  }
}

extern "C" void kernel_launch(void* const* d_in, const int* in_sizes, int n_in,
                              void* d_out, int out_size, void* d_ws, size_t ws_size,
                              hipStream_t stream) {
  const void* x     = d_in[0];
  const int*  pidx  = (const int*)d_in[1];
  const void* Wq    = d_in[2];
  const void* bq    = d_in[3];
  const void* Wk    = d_in[4];
  const void* bk    = d_in[5];
  const void* Wv    = d_in[6];
  const void* bv    = d_in[7];
  const void* seeds = d_in[8];
  const void* al    = d_in[9];
  const void* be    = d_in[10];

  char* ws = (char*)d_ws;
  ushort_t* Qb   = (ushort_t*)(ws + OFF_Q);
  ushort_t* Kb   = (ushort_t*)(ws + OFF_K);
  ushort_t* Vb   = (ushort_t*)(ws + OFF_V);
  ushort_t* locS = (ushort_t*)(ws + OFF_LOC);
  ushort_t* rpk  = (ushort_t*)(ws + OFF_RPK);
  ushort_t* rpv  = (ushort_t*)(ws + OFF_RPV);
  ushort_t* xc   = (ushort_t*)(ws + OFF_XC);
  ushort_t* wc   = (ushort_t*)(ws + OFF_WC);
  float*    scal = (float*)   (ws + OFF_SCAL);
  uint32*   flags= (uint32*)  (ws + OFF_FLAG);

  k_detect<<<1, 64, 0, stream>>>((const uint32*)x, (const ushort_t*)be, flags);
  k_convert<<<dim3(4096, 2), 256, 0, stream>>>(x, Wq, bq, Wk, bk, Wv, bv, seeds, al, be,
                                               xc, wc, scal, flags);
  k_qkv<<<dim3(8, 512, 3), 256, 0, stream>>>(xc, wc, Qb, Kb, Vb);
  k_fine<<<dim3(128, 4), 256, 0, stream>>>(Qb, Kb, Vb, pidx, wc, locS, rpk, rpv);
  k_cross<<<2048, 256, 0, stream>>>(Qb, Vb, rpk, rpv, locS, scal, (float*)d_out);
}

// Round 7
// 1626.820 us; speedup vs baseline: 2.0438x; 2.0438x over previous
//
#include <hip/hip_runtime.h>
#include <hip/hip_bf16.h>

// PCGTConvLayer round 7: k_cross rewritten as chunked-MFMA flash-attention
// (64 nodes x 1 head per block, online softmax, P via LDS A-layout transform,
// PV from transposed reps rvT). k_fine additionally emits rvT[h][d][r].
// Separate k_combine produces the f32 output. k_detect/convert/qkv/fine
// pipeline otherwise unchanged (verified round 5/6).
// N=32768 IN=256 D=128 H=4 M=4 KP=128 S=256, SCALE=sqrt(128).

#define INV_SCALE 0.08838834764831845f

typedef __attribute__((ext_vector_type(8))) short bf16x8;
typedef __attribute__((ext_vector_type(4))) float floatx4;
typedef unsigned short ushort_t;
typedef unsigned int uint32;

// ---- ws layout (bytes) ----
#define OFF_Q    0ull            // bf16 [32768][512]
#define OFF_K    33554432ull     // bf16 [32768][512]
#define OFF_V    67108864ull     // bf16 [32768][512]
#define OFF_LOC  100663296ull    // bf16 [32768][128]
#define OFF_RPK  109051904ull    // bf16 [512][4][128]   (r=k*4+m, h, d)
#define OFF_RPV  109576192ull    // bf16 [512][4][128]   (legacy, unused by cross)
#define OFF_XC   110100480ull    // bf16 [32768][256]
#define OFF_WC   126877696ull    // bf16 weights/biases/seeds
#define OFF_SCAL 127671296ull    // f32 [2]
#define OFF_FLAG 127671304ull    // u32 [2]
#define OFF_RVT  127672320ull    // bf16 [4][128][512]   (h, d, r) transposed reps_v
#define OFF_GLB  128196608ull    // bf16 [32768][512]    per-head global out

#define WC_WQ 0
#define WC_WK 131072
#define WC_WV 262144
#define WC_BQ 393216
#define WC_BK 393728
#define WC_BV 394240
#define WC_SEED 394752
#define WC_TOT 396800

static __device__ __forceinline__ float bflo(uint32 u) {
  return __uint_as_float(u << 16);
}
static __device__ __forceinline__ float bfhi(uint32 u) {
  return __uint_as_float(u & 0xffff0000u);
}
static __device__ __forceinline__ float bf2f(ushort_t u) {
  return __uint_as_float(((uint32)u) << 16);
}
static __device__ __forceinline__ ushort_t f2bf(float f) {
  uint32 x = __float_as_uint(f);
  uint32 r = x + 0x7fffu + ((x >> 16) & 1u);
  return (ushort_t)(r >> 16);
}
static __device__ __forceinline__ uint32 pack2bf(float a, float b) {
  return (uint32)f2bf(a) | ((uint32)f2bf(b) << 16);
}

// ---------------------------------------------------------------------------
// K0: dtype detection.
// ---------------------------------------------------------------------------
__global__ __launch_bounds__(64) void k_detect(const uint32* __restrict__ xw,
                                               const ushort_t* __restrict__ betaRaw,
                                               uint32* __restrict__ flags) {
  const int lane = threadIdx.x;
  const uint32 w = xw[lane * 137 + 3];
  const int e = (w >> 7) & 0xff;
  const unsigned long long b = __ballot(e >= 100 && e <= 140);
  if (lane == 0) {
    flags[0] = (__popcll(b) >= 48) ? 1u : 0u;
    flags[1] = (betaRaw[0] != 0) ? 1u : 0u;
  }
}

// ---------------------------------------------------------------------------
// K1: canonicalize float inputs to bf16.
// ---------------------------------------------------------------------------
static __device__ __forceinline__ void conv8(const void* src, long j, int isB,
                                             ushort_t* dst) {
  if (isB) {
    *reinterpret_cast<uint4*>(dst) =
        *reinterpret_cast<const uint4*>(reinterpret_cast<const ushort_t*>(src) + j);
  } else {
    const float* f = reinterpret_cast<const float*>(src) + j;
    const float4 a = *reinterpret_cast<const float4*>(f);
    const float4 b = *reinterpret_cast<const float4*>(f + 4);
    uint4 o;
    o.x = pack2bf(a.x, a.y); o.y = pack2bf(a.z, a.w);
    o.z = pack2bf(b.x, b.y); o.w = pack2bf(b.z, b.w);
    *reinterpret_cast<uint4*>(dst) = o;
  }
}

__global__ __launch_bounds__(256) void k_convert(
    const void* __restrict__ x,
    const void* __restrict__ Wq, const void* __restrict__ bq,
    const void* __restrict__ Wk, const void* __restrict__ bk,
    const void* __restrict__ Wv, const void* __restrict__ bv,
    const void* __restrict__ seeds, const void* __restrict__ alpha,
    const void* __restrict__ beta,
    ushort_t* __restrict__ xc, ushort_t* __restrict__ wc,
    float* __restrict__ scal, const uint32* __restrict__ flags)
{
  const int isB = (int)flags[0];
  const long i8 = ((long)blockIdx.x * 256 + threadIdx.x) * 8;
  if (blockIdx.y == 0) {
    conv8(x, i8, isB, xc + i8);
  } else {
    if (i8 < WC_TOT) {
      const void* src; long j;
      if (i8 < WC_WK)        { src = Wq;    j = i8; }
      else if (i8 < WC_WV)   { src = Wk;    j = i8 - WC_WK; }
      else if (i8 < WC_BQ)   { src = Wv;    j = i8 - WC_WV; }
      else if (i8 < WC_BK)   { src = bq;    j = i8 - WC_BQ; }
      else if (i8 < WC_BV)   { src = bk;    j = i8 - WC_BK; }
      else if (i8 < WC_SEED) { src = bv;    j = i8 - WC_BV; }
      else                   { src = seeds; j = i8 - WC_SEED; }
      conv8(src, j, isB, wc + i8);
    }
    if (blockIdx.x == 0 && threadIdx.x == 0) {
      const int isBS = (int)flags[1];
      scal[0] = isBS ? bf2f(reinterpret_cast<const ushort_t*>(alpha)[0])
                     : reinterpret_cast<const float*>(alpha)[0];
      scal[1] = isBS ? bf2f(reinterpret_cast<const ushort_t*>(beta)[0])
                     : reinterpret_cast<const float*>(beta)[0];
    }
  }
}

// ---------------------------------------------------------------------------
// K2: QKV projection GEMM (verified CHK1).
// ---------------------------------------------------------------------------
__global__ __launch_bounds__(256) void k_qkv(
    const ushort_t* __restrict__ xc, const ushort_t* __restrict__ wc,
    ushort_t* __restrict__ Qb, ushort_t* __restrict__ Kb, ushort_t* __restrict__ Vb)
{
  const int sel = blockIdx.z;
  const ushort_t* W    = wc + (sel == 0 ? WC_WQ : (sel == 1 ? WC_WK : WC_WV));
  const ushort_t* bias = wc + (sel == 0 ? WC_BQ : (sel == 1 ? WC_BK : WC_BV));
  ushort_t* out        = sel == 0 ? Qb : (sel == 1 ? Kb : Vb);

  const int mTile = blockIdx.y * 64;
  const int nTile = blockIdx.x * 64;
  const int tid = threadIdx.x;
  const int lane = tid & 63;
  const int wv = tid >> 6;
  const int waveM = wv >> 1, waveN = wv & 1;
  const int l16 = lane & 15, quad = lane >> 4;

  __shared__ __align__(16) ushort_t As[64 * 32];
  __shared__ __align__(16) ushort_t Bs[64 * 32];

  floatx4 acc[2][2] = {};

  const int ar = tid >> 2, ac = (tid & 3) * 8;
  const int bkk = tid >> 3, bj = (tid & 7) * 8;

  for (int k0 = 0; k0 < 256; k0 += 32) {
    uint4 av = *reinterpret_cast<const uint4*>(xc + (size_t)(mTile + ar) * 256 + k0 + ac);
    *reinterpret_cast<uint4*>(&As[ar * 32 + ac]) = av;

    uint4 bvv = *reinterpret_cast<const uint4*>(W + (size_t)(k0 + bkk) * 512 + nTile + bj);
    const ushort_t* bu = reinterpret_cast<const ushort_t*>(&bvv);
#pragma unroll
    for (int i = 0; i < 8; ++i) Bs[(bj + i) * 32 + bkk] = bu[i];
    __syncthreads();

    bf16x8 aF[2], bF[2];
#pragma unroll
    for (int mi = 0; mi < 2; ++mi)
      aF[mi] = *reinterpret_cast<const bf16x8*>(&As[(waveM * 32 + mi * 16 + l16) * 32 + quad * 8]);
#pragma unroll
    for (int ni = 0; ni < 2; ++ni)
      bF[ni] = *reinterpret_cast<const bf16x8*>(&Bs[(waveN * 32 + ni * 16 + l16) * 32 + quad * 8]);
#pragma unroll
    for (int mi = 0; mi < 2; ++mi)
#pragma unroll
      for (int ni = 0; ni < 2; ++ni)
        acc[mi][ni] = __builtin_amdgcn_mfma_f32_16x16x32_bf16(aF[mi], bF[ni], acc[mi][ni], 0, 0, 0);
    __syncthreads();
  }

#pragma unroll
  for (int mi = 0; mi < 2; ++mi) {
#pragma unroll
    for (int ni = 0; ni < 2; ++ni) {
      const int col = nTile + waveN * 32 + ni * 16 + l16;
      const float bf = bf2f(bias[col]);
#pragma unroll
      for (int r = 0; r < 4; ++r) {
        const int row = mTile + waveM * 32 + mi * 16 + quad * 4 + r;
        out[(size_t)row * 512 + col] = f2bf(acc[mi][ni][r] + bf);
      }
    }
  }
}

// ---------------------------------------------------------------------------
// K3: fused fine attention (verified CHK2/CHK3) + NEW: rvT transposed output.
// ---------------------------------------------------------------------------
__global__ __launch_bounds__(256) void k_fine(
    const ushort_t* __restrict__ Qb, const ushort_t* __restrict__ Kb,
    const ushort_t* __restrict__ Vb, const int* __restrict__ pidx_all,
    const ushort_t* __restrict__ wc,
    ushort_t* __restrict__ locS, ushort_t* __restrict__ rpk,
    ushort_t* __restrict__ rpv, ushort_t* __restrict__ rvT)
{
  const int k = blockIdx.x, pg = blockIdx.y;
  const int tid = threadIdx.x, lane = tid & 63, wv = tid >> 6;
  const int* pidx = pidx_all + k * 256;

  __shared__ __align__(16) ushort_t SB[128 * 256];
  const uint32* SBU = reinterpret_cast<const uint32*>(SB);

  float accA[16], accB[16];
  float P0[16], P1[16], P2[16], P3[16];
#pragma unroll
  for (int r = 0; r < 16; ++r) { accA[r] = 0.f; accB[r] = 0.f; }

  for (int h = 0; h < 4; ++h) {
#pragma unroll
    for (int i = 0; i < 16; ++i) {
      const int e8 = tid + 256 * i;
      const int q = e8 >> 4, dc = (e8 & 15) * 8;
      uint4 kv = *reinterpret_cast<const uint4*>(Kb + (size_t)pidx[q] * 512 + h * 128 + dc);
      const ushort_t* ku = reinterpret_cast<const ushort_t*>(&kv);
      const int qp = q >> 1, qb = q & 1;
#pragma unroll
      for (int j = 0; j < 8; ++j) {
        const int d = dc + j;
        SB[d * 256 + (((qp ^ (d & 31)) << 1) | qb)] = ku[j];
      }
    }
    __syncthreads();

#pragma unroll
    for (int r = 0; r < 16; ++r) {
      const int p = pg * 64 + wv * 16 + r;
      const uint32* qsrc = reinterpret_cast<const uint32*>(Qb + (size_t)pidx[p] * 512 + h * 128);
      float s00 = 0.f, s01 = 0.f, s10 = 0.f, s11 = 0.f;
#pragma unroll 8
      for (int dc = 0; dc < 64; ++dc) {
        const uint32 qv = qsrc[dc];
        const float q0 = bflo(qv), q1 = bfhi(qv);
        const int d0 = dc * 2, d1 = d0 + 1;
        const int c0 = lane ^ (d0 & 31);
        const int c1 = lane ^ (d1 & 31);
        const uint32 u00 = SBU[d0 * 128 + c0];
        const uint32 u01 = SBU[d0 * 128 + c0 + 64];
        const uint32 u10 = SBU[d1 * 128 + c1];
        const uint32 u11 = SBU[d1 * 128 + c1 + 64];
        s00 += q0 * bflo(u00) + q1 * bflo(u10);
        s01 += q0 * bfhi(u00) + q1 * bfhi(u10);
        s10 += q0 * bflo(u01) + q1 * bflo(u11);
        s11 += q0 * bfhi(u01) + q1 * bfhi(u11);
      }
      s00 *= INV_SCALE; s01 *= INV_SCALE; s10 *= INV_SCALE; s11 *= INV_SCALE;
      float mx = fmaxf(fmaxf(s00, s01), fmaxf(s10, s11));
#pragma unroll
      for (int off = 32; off >= 1; off >>= 1) mx = fmaxf(mx, __shfl_xor(mx, off));
      const float e00 = __expf(s00 - mx), e01 = __expf(s01 - mx);
      const float e10 = __expf(s10 - mx), e11 = __expf(s11 - mx);
      float sm = e00 + e01 + e10 + e11;
#pragma unroll
      for (int off = 32; off >= 1; off >>= 1) sm += __shfl_xor(sm, off);
      const float inv = 1.0f / sm;
      P0[r] = e00 * inv; P1[r] = e01 * inv; P2[r] = e10 * inv; P3[r] = e11 * inv;
    }

    float q00 = 0.f, q01 = 0.f, q10 = 0.f, q11 = 0.f;
    if (pg == h) {
      const uint32* ssrc = reinterpret_cast<const uint32*>(wc + WC_SEED + (size_t)(wv * 4 + h) * 128);
      float s00 = 0.f, s01 = 0.f, s10 = 0.f, s11 = 0.f;
#pragma unroll 8
      for (int dc = 0; dc < 64; ++dc) {
        const uint32 qv = ssrc[dc];
        const float a0 = bflo(qv), a1 = bfhi(qv);
        const int d0 = dc * 2, d1 = d0 + 1;
        const int c0 = lane ^ (d0 & 31);
        const int c1 = lane ^ (d1 & 31);
        const uint32 u00 = SBU[d0 * 128 + c0];
        const uint32 u01 = SBU[d0 * 128 + c0 + 64];
        const uint32 u10 = SBU[d1 * 128 + c1];
        const uint32 u11 = SBU[d1 * 128 + c1 + 64];
        s00 += a0 * bflo(u00) + a1 * bflo(u10);
        s01 += a0 * bfhi(u00) + a1 * bfhi(u10);
        s10 += a0 * bflo(u01) + a1 * bflo(u11);
        s11 += a0 * bfhi(u01) + a1 * bfhi(u11);
      }
      s00 *= INV_SCALE; s01 *= INV_SCALE; s10 *= INV_SCALE; s11 *= INV_SCALE;
      float mx = fmaxf(fmaxf(s00, s01), fmaxf(s10, s11));
#pragma unroll
      for (int off = 32; off >= 1; off >>= 1) mx = fmaxf(mx, __shfl_xor(mx, off));
      const float e00 = __expf(s00 - mx), e01 = __expf(s01 - mx);
      const float e10 = __expf(s10 - mx), e11 = __expf(s11 - mx);
      float sm = e00 + e01 + e10 + e11;
#pragma unroll
      for (int off = 32; off >= 1; off >>= 1) sm += __shfl_xor(sm, off);
      const float inv = 1.0f / sm;
      q00 = e00 * inv; q01 = e01 * inv; q10 = e10 * inv; q11 = e11 * inv;

      float rk0 = 0.f, rk1 = 0.f;
      const int d0 = 2 * lane, d1 = 2 * lane + 1;
#pragma unroll 4
      for (int qp = 0; qp < 64; ++qp) {
        const float pa = __shfl(q00, qp), pb = __shfl(q01, qp);
        const float pc = __shfl(q10, qp), pd = __shfl(q11, qp);
        const int c0 = qp ^ (d0 & 31);
        const int c1 = qp ^ (d1 & 31);
        const uint32 u0  = SBU[d0 * 128 + c0];
        const uint32 u0b = SBU[d0 * 128 + c0 + 64];
        const uint32 u1  = SBU[d1 * 128 + c1];
        const uint32 u1b = SBU[d1 * 128 + c1 + 64];
        rk0 += pa * bflo(u0) + pb * bfhi(u0) + pc * bflo(u0b) + pd * bfhi(u0b);
        rk1 += pa * bflo(u1) + pb * bfhi(u1) + pc * bflo(u1b) + pd * bfhi(u1b);
      }
      reinterpret_cast<uint32*>(rpk + ((size_t)((k * 4 + wv) * 4 + h)) * 128)[lane] = pack2bf(rk0, rk1);
    }
    __syncthreads();

#pragma unroll
    for (int i = 0; i < 16; ++i) {
      const int e8 = tid + 256 * i;
      const int q = e8 >> 4, dc = (e8 & 15) * 8;
      uint4 vv = *reinterpret_cast<const uint4*>(Vb + (size_t)pidx[q] * 512 + h * 128 + dc);
      *reinterpret_cast<uint4*>(&SB[q * 128 + dc]) = vv;
    }
    __syncthreads();

#pragma unroll
    for (int r = 0; r < 16; ++r) {
      float a0 = 0.f, a1 = 0.f;
#pragma unroll 4
      for (int qp = 0; qp < 64; ++qp) {
        const float pa = __shfl(P0[r], qp);
        const float pb = __shfl(P1[r], qp);
        const float pc = __shfl(P2[r], qp);
        const float pd = __shfl(P3[r], qp);
        const uint32 v00 = SBU[(2 * qp) * 64 + lane];
        const uint32 v01 = SBU[(2 * qp + 1) * 64 + lane];
        const uint32 v10 = SBU[(128 + 2 * qp) * 64 + lane];
        const uint32 v11 = SBU[(129 + 2 * qp) * 64 + lane];
        a0 += pa * bflo(v00) + pb * bflo(v01) + pc * bflo(v10) + pd * bflo(v11);
        a1 += pa * bfhi(v00) + pb * bfhi(v01) + pc * bfhi(v10) + pd * bfhi(v11);
      }
      accA[r] += a0; accB[r] += a1;
    }

    if (pg == h) {
      float rv0 = 0.f, rv1 = 0.f;
#pragma unroll 4
      for (int qp = 0; qp < 64; ++qp) {
        const float pa = __shfl(q00, qp), pb = __shfl(q01, qp);
        const float pc = __shfl(q10, qp), pd = __shfl(q11, qp);
        const uint32 v00 = SBU[(2 * qp) * 64 + lane];
        const uint32 v01 = SBU[(2 * qp + 1) * 64 + lane];
        const uint32 v10 = SBU[(128 + 2 * qp) * 64 + lane];
        const uint32 v11 = SBU[(129 + 2 * qp) * 64 + lane];
        rv0 += pa * bflo(v00) + pb * bflo(v01) + pc * bflo(v10) + pd * bflo(v11);
        rv1 += pa * bfhi(v00) + pb * bfhi(v01) + pc * bfhi(v10) + pd * bfhi(v11);
      }
      reinterpret_cast<uint32*>(rpv + ((size_t)((k * 4 + wv) * 4 + h)) * 128)[lane] = pack2bf(rv0, rv1);
      // NEW: transposed reps_v for MFMA cross-attention: rvT[h][d][r]
      const int rrep = k * 4 + wv;
      rvT[(size_t)(h * 128 + 2 * lane) * 512 + rrep]     = f2bf(rv0);
      rvT[(size_t)(h * 128 + 2 * lane + 1) * 512 + rrep] = f2bf(rv1);
    }
    __syncthreads();
  }

#pragma unroll
  for (int r = 0; r < 16; ++r) {
    const int p = pg * 64 + wv * 16 + r;
    const int n = pidx[p];
    reinterpret_cast<uint32*>(locS)[(size_t)n * 64 + lane] =
        pack2bf(accA[r] * 0.25f, accB[r] * 0.25f);
  }
}

// ---------------------------------------------------------------------------
// K4: MFMA cross-attention. Block = 64 nodes x 1 head (grid 512 x 4), 4 waves,
// each wave a 16-node stripe. Loops 8 chunks of 64 reps: QK^T via MFMA,
// online softmax in C-layout regs, P -> LDS (A-layout), PV via MFMA with
// rvT (B operand = RV^T). LDS rows padded: 136 bf16 (272B) / 72 bf16 (144B)
// -> 16B-aligned, bank-rotation 4 (<=2-way conflicts, free per m136).
// Writes per-head global out to glb[n][h*128+d].
// ---------------------------------------------------------------------------
__global__ __launch_bounds__(256) void k_cross(
    const ushort_t* __restrict__ Qb, const ushort_t* __restrict__ rpk,
    const ushort_t* __restrict__ rvT, ushort_t* __restrict__ glb)
{
  const int h = blockIdx.y;
  const int n0 = blockIdx.x * 64;
  const int tid = threadIdx.x, lane = tid & 63, wv = tid >> 6;
  const int l16 = lane & 15, quad = lane >> 4;

  __shared__ __align__(16) ushort_t Qs[64 * 136];    // 17408 B
  __shared__ __align__(16) ushort_t Bs[128 * 72];    // 18432 B (union RK 64x136 / RVt 128x72)
  __shared__ __align__(16) ushort_t Ps[4][16 * 72];  // 9216 B

  // stage Q tile [64][128] -> Qs[64][136]
#pragma unroll
  for (int i = 0; i < 4; ++i) {
    const int e = tid + 256 * i;
    const int r = e >> 4, c8 = (e & 15) * 8;
    uint4 v = *reinterpret_cast<const uint4*>(Qb + (size_t)(n0 + r) * 512 + h * 128 + c8);
    *reinterpret_cast<uint4*>(&Qs[r * 136 + c8]) = v;
  }

  floatx4 O[8] = {};
  float m_i[4], l_i[4];
#pragma unroll
  for (int r = 0; r < 4; ++r) { m_i[r] = -3e38f; l_i[r] = 0.f; }

  for (int c = 0; c < 8; ++c) {
    __syncthreads();   // prev-chunk PV reads done; Q staged (first iter)
    // stage RK chunk [64][128] -> Bs[64][136]
#pragma unroll
    for (int i = 0; i < 4; ++i) {
      const int e = tid + 256 * i;
      const int r = e >> 4, c8 = (e & 15) * 8;
      uint4 v = *reinterpret_cast<const uint4*>(rpk + ((size_t)((c * 64 + r) * 4 + h)) * 128 + c8);
      *reinterpret_cast<uint4*>(&Bs[r * 136 + c8]) = v;
    }
    __syncthreads();

    // scores: S[16 nodes x 64 reps] per wave
    floatx4 S[4] = {};
#pragma unroll
    for (int ks = 0; ks < 4; ++ks) {
      bf16x8 a = *reinterpret_cast<const bf16x8*>(&Qs[(wv * 16 + l16) * 136 + ks * 32 + quad * 8]);
#pragma unroll
      for (int nt = 0; nt < 4; ++nt) {
        bf16x8 b = *reinterpret_cast<const bf16x8*>(&Bs[(nt * 16 + l16) * 136 + ks * 32 + quad * 8]);
        S[nt] = __builtin_amdgcn_mfma_f32_16x16x32_bf16(a, b, S[nt], 0, 0, 0);
      }
    }
#pragma unroll
    for (int nt = 0; nt < 4; ++nt)
#pragma unroll
      for (int r = 0; r < 4; ++r) S[nt][r] *= INV_SCALE;

    // online softmax per row (row = quad*4+r, spread across 16 l16 lanes)
#pragma unroll
    for (int r = 0; r < 4; ++r) {
      float cm = fmaxf(fmaxf(S[0][r], S[1][r]), fmaxf(S[2][r], S[3][r]));
#pragma unroll
      for (int off = 1; off <= 8; off <<= 1) cm = fmaxf(cm, __shfl_xor(cm, off));
      const float mn = fmaxf(m_i[r], cm);
      const float sc = __expf(m_i[r] - mn);
      m_i[r] = mn;
      l_i[r] *= sc;
#pragma unroll
      for (int nt = 0; nt < 8; ++nt) O[nt][r] *= sc;
      float ps = 0.f;
#pragma unroll
      for (int nt = 0; nt < 4; ++nt) {
        const float p = __expf(S[nt][r] - mn);
        ps += p;
        Ps[wv][(quad * 4 + r) * 72 + nt * 16 + l16] = f2bf(p);
      }
#pragma unroll
      for (int off = 1; off <= 8; off <<= 1) ps += __shfl_xor(ps, off);
      l_i[r] += ps;
    }
    __syncthreads();   // RK reads done; Ps visible

    // stage RVt chunk [128][64] -> Bs[128][72]
#pragma unroll
    for (int i = 0; i < 4; ++i) {
      const int e = tid + 256 * i;
      const int d = e >> 3, c8 = (e & 7) * 8;
      uint4 v = *reinterpret_cast<const uint4*>(rvT + ((size_t)(h * 128 + d)) * 512 + c * 64 + c8);
      *reinterpret_cast<uint4*>(&Bs[d * 72 + c8]) = v;
    }
    __syncthreads();

    // PV: O[16 x 128] += P[16 x 64] * RV[64 x 128]
#pragma unroll
    for (int ks = 0; ks < 2; ++ks) {
      bf16x8 a = *reinterpret_cast<const bf16x8*>(&Ps[wv][l16 * 72 + ks * 32 + quad * 8]);
#pragma unroll
      for (int nt = 0; nt < 8; ++nt) {
        bf16x8 b = *reinterpret_cast<const bf16x8*>(&Bs[(nt * 16 + l16) * 72 + ks * 32 + quad * 8]);
        O[nt] = __builtin_amdgcn_mfma_f32_16x16x32_bf16(a, b, O[nt], 0, 0, 0);
      }
    }
  }

  // epilogue: normalize and store per-head global out
#pragma unroll
  for (int r = 0; r < 4; ++r) {
    const float inv = 1.0f / l_i[r];
    const int n = n0 + wv * 16 + quad * 4 + r;
#pragma unroll
    for (int nt = 0; nt < 8; ++nt)
      glb[(size_t)n * 512 + h * 128 + nt * 16 + l16] = f2bf(O[nt][r] * inv);
  }
}

// ---------------------------------------------------------------------------
// K5: combine -> f32 output.
// ---------------------------------------------------------------------------
__global__ __launch_bounds__(256) void k_combine(
    const ushort_t* __restrict__ locS, const ushort_t* __restrict__ glb,
    const ushort_t* __restrict__ Vb, const float* __restrict__ scal,
    float* __restrict__ out)
{
  const int t = blockIdx.x * 256 + threadIdx.x;   // over N*64
  const int n = t >> 6, dp = t & 63;
  const float alpha = 1.0f / (1.0f + __expf(-scal[0]));
  const float beta = scal[1];
  const uint32 lv = reinterpret_cast<const uint32*>(locS)[(size_t)n * 64 + dp];
  float g0 = 0.f, g1 = 0.f, v0 = 0.f, v1 = 0.f;
#pragma unroll
  for (int hh = 0; hh < 4; ++hh) {
    const uint32 gv = *reinterpret_cast<const uint32*>(glb + (size_t)n * 512 + hh * 128 + 2 * dp);
    const uint32 vv = *reinterpret_cast<const uint32*>(Vb + (size_t)n * 512 + hh * 128 + 2 * dp);
    g0 += bflo(gv); g1 += bfhi(gv);
    v0 += bflo(vv); v1 += bfhi(vv);
  }
  const float r0 = alpha * bflo(lv) + (1.0f - alpha) * g0 * 0.25f + beta * v0 * 0.25f;
  const float r1 = alpha * bfhi(lv) + (1.0f - alpha) * g1 * 0.25f + beta * v1 * 0.25f;
  reinterpret_cast<float2*>(out)[(size_t)n * 64 + dp] = make_float2(r0, r1);
}

extern "C" void kernel_launch(void* const* d_in, const int* in_sizes, int n_in,
                              void* d_out, int out_size, void* d_ws, size_t ws_size,
                              hipStream_t stream) {
  const void* x     = d_in[0];
  const int*  pidx  = (const int*)d_in[1];
  const void* Wq    = d_in[2];
  const void* bq    = d_in[3];
  const void* Wk    = d_in[4];
  const void* bk    = d_in[5];
  const void* Wv    = d_in[6];
  const void* bv    = d_in[7];
  const void* seeds = d_in[8];
  const void* al    = d_in[9];
  const void* be    = d_in[10];

  char* ws = (char*)d_ws;
  ushort_t* Qb   = (ushort_t*)(ws + OFF_Q);
  ushort_t* Kb   = (ushort_t*)(ws + OFF_K);
  ushort_t* Vb   = (ushort_t*)(ws + OFF_V);
  ushort_t* locS = (ushort_t*)(ws + OFF_LOC);
  ushort_t* rpk  = (ushort_t*)(ws + OFF_RPK);
  ushort_t* rpv  = (ushort_t*)(ws + OFF_RPV);
  ushort_t* xc   = (ushort_t*)(ws + OFF_XC);
  ushort_t* wc   = (ushort_t*)(ws + OFF_WC);
  float*    scal = (float*)   (ws + OFF_SCAL);
  uint32*   flags= (uint32*)  (ws + OFF_FLAG);
  ushort_t* rvT  = (ushort_t*)(ws + OFF_RVT);
  ushort_t* glb  = (ushort_t*)(ws + OFF_GLB);

  k_detect<<<1, 64, 0, stream>>>((const uint32*)x, (const ushort_t*)be, flags);
  k_convert<<<dim3(4096, 2), 256, 0, stream>>>(x, Wq, bq, Wk, bk, Wv, bv, seeds, al, be,
                                               xc, wc, scal, flags);
  k_qkv<<<dim3(8, 512, 3), 256, 0, stream>>>(xc, wc, Qb, Kb, Vb);
  k_fine<<<dim3(128, 4), 256, 0, stream>>>(Qb, Kb, Vb, pidx, wc, locS, rpk, rpv, rvT);
  k_cross<<<dim3(512, 4), 256, 0, stream>>>(Qb, rpk, rvT, glb);
  k_combine<<<8192, 256, 0, stream>>>(locS, glb, Vb, scal, (float*)d_out);
}

// Round 8
// 436.766 us; speedup vs baseline: 7.6125x; 3.7247x over previous
//
#include <hip/hip_runtime.h>
#include <hip/hip_bf16.h>

// PCGTConvLayer round 8: k_fine rewritten as chunked-MFMA flash attention
// (same verified template as k_cross). Pooling/reps split into k_pool
// (verbatim verified scalar code from old k_fine). Pipeline:
// detect -> convert -> qkv -> pool -> fine(MFMA) -> cross(MFMA) -> combine.
// N=32768 IN=256 D=128 H=4 M=4 KP=128 S=256, SCALE=sqrt(128).

#define INV_SCALE 0.08838834764831845f

typedef __attribute__((ext_vector_type(8))) short bf16x8;
typedef __attribute__((ext_vector_type(4))) float floatx4;
typedef unsigned short ushort_t;
typedef unsigned int uint32;

// ---- ws layout (bytes) ----
#define OFF_Q    0ull            // bf16 [32768][512]
#define OFF_K    33554432ull     // bf16 [32768][512]
#define OFF_V    67108864ull     // bf16 [32768][512]
#define OFF_LOC  100663296ull    // bf16 [32768][128]
#define OFF_RPK  109051904ull    // bf16 [512][4][128]
#define OFF_RPV  109576192ull    // (unused)
#define OFF_XC   110100480ull    // bf16 [32768][256]
#define OFF_WC   126877696ull    // bf16 weights/biases/seeds
#define OFF_SCAL 127671296ull    // f32 [2]
#define OFF_FLAG 127671304ull    // u32 [2]
#define OFF_RVT  127672320ull    // bf16 [4][128][512]  (h, d, r)
#define OFF_GLB  128196608ull    // bf16 [32768][512]

#define WC_WQ 0
#define WC_WK 131072
#define WC_WV 262144
#define WC_BQ 393216
#define WC_BK 393728
#define WC_BV 394240
#define WC_SEED 394752
#define WC_TOT 396800

static __device__ __forceinline__ float bflo(uint32 u) {
  return __uint_as_float(u << 16);
}
static __device__ __forceinline__ float bfhi(uint32 u) {
  return __uint_as_float(u & 0xffff0000u);
}
static __device__ __forceinline__ float bf2f(ushort_t u) {
  return __uint_as_float(((uint32)u) << 16);
}
static __device__ __forceinline__ ushort_t f2bf(float f) {
  uint32 x = __float_as_uint(f);
  uint32 r = x + 0x7fffu + ((x >> 16) & 1u);
  return (ushort_t)(r >> 16);
}
static __device__ __forceinline__ uint32 pack2bf(float a, float b) {
  return (uint32)f2bf(a) | ((uint32)f2bf(b) << 16);
}

// ---------------------------------------------------------------------------
__global__ __launch_bounds__(64) void k_detect(const uint32* __restrict__ xw,
                                               const ushort_t* __restrict__ betaRaw,
                                               uint32* __restrict__ flags) {
  const int lane = threadIdx.x;
  const uint32 w = xw[lane * 137 + 3];
  const int e = (w >> 7) & 0xff;
  const unsigned long long b = __ballot(e >= 100 && e <= 140);
  if (lane == 0) {
    flags[0] = (__popcll(b) >= 48) ? 1u : 0u;
    flags[1] = (betaRaw[0] != 0) ? 1u : 0u;
  }
}

// ---------------------------------------------------------------------------
static __device__ __forceinline__ void conv8(const void* src, long j, int isB,
                                             ushort_t* dst) {
  if (isB) {
    *reinterpret_cast<uint4*>(dst) =
        *reinterpret_cast<const uint4*>(reinterpret_cast<const ushort_t*>(src) + j);
  } else {
    const float* f = reinterpret_cast<const float*>(src) + j;
    const float4 a = *reinterpret_cast<const float4*>(f);
    const float4 b = *reinterpret_cast<const float4*>(f + 4);
    uint4 o;
    o.x = pack2bf(a.x, a.y); o.y = pack2bf(a.z, a.w);
    o.z = pack2bf(b.x, b.y); o.w = pack2bf(b.z, b.w);
    *reinterpret_cast<uint4*>(dst) = o;
  }
}

__global__ __launch_bounds__(256) void k_convert(
    const void* __restrict__ x,
    const void* __restrict__ Wq, const void* __restrict__ bq,
    const void* __restrict__ Wk, const void* __restrict__ bk,
    const void* __restrict__ Wv, const void* __restrict__ bv,
    const void* __restrict__ seeds, const void* __restrict__ alpha,
    const void* __restrict__ beta,
    ushort_t* __restrict__ xc, ushort_t* __restrict__ wc,
    float* __restrict__ scal, const uint32* __restrict__ flags)
{
  const int isB = (int)flags[0];
  const long i8 = ((long)blockIdx.x * 256 + threadIdx.x) * 8;
  if (blockIdx.y == 0) {
    conv8(x, i8, isB, xc + i8);
  } else {
    if (i8 < WC_TOT) {
      const void* src; long j;
      if (i8 < WC_WK)        { src = Wq;    j = i8; }
      else if (i8 < WC_WV)   { src = Wk;    j = i8 - WC_WK; }
      else if (i8 < WC_BQ)   { src = Wv;    j = i8 - WC_WV; }
      else if (i8 < WC_BK)   { src = bq;    j = i8 - WC_BQ; }
      else if (i8 < WC_BV)   { src = bk;    j = i8 - WC_BK; }
      else if (i8 < WC_SEED) { src = bv;    j = i8 - WC_BV; }
      else                   { src = seeds; j = i8 - WC_SEED; }
      conv8(src, j, isB, wc + i8);
    }
    if (blockIdx.x == 0 && threadIdx.x == 0) {
      const int isBS = (int)flags[1];
      scal[0] = isBS ? bf2f(reinterpret_cast<const ushort_t*>(alpha)[0])
                     : reinterpret_cast<const float*>(alpha)[0];
      scal[1] = isBS ? bf2f(reinterpret_cast<const ushort_t*>(beta)[0])
                     : reinterpret_cast<const float*>(beta)[0];
    }
  }
}

// ---------------------------------------------------------------------------
// K2: QKV projection GEMM (verified CHK1).
// ---------------------------------------------------------------------------
__global__ __launch_bounds__(256) void k_qkv(
    const ushort_t* __restrict__ xc, const ushort_t* __restrict__ wc,
    ushort_t* __restrict__ Qb, ushort_t* __restrict__ Kb, ushort_t* __restrict__ Vb)
{
  const int sel = blockIdx.z;
  const ushort_t* W    = wc + (sel == 0 ? WC_WQ : (sel == 1 ? WC_WK : WC_WV));
  const ushort_t* bias = wc + (sel == 0 ? WC_BQ : (sel == 1 ? WC_BK : WC_BV));
  ushort_t* out        = sel == 0 ? Qb : (sel == 1 ? Kb : Vb);

  const int mTile = blockIdx.y * 64;
  const int nTile = blockIdx.x * 64;
  const int tid = threadIdx.x;
  const int lane = tid & 63;
  const int wv = tid >> 6;
  const int waveM = wv >> 1, waveN = wv & 1;
  const int l16 = lane & 15, quad = lane >> 4;

  __shared__ __align__(16) ushort_t As[64 * 32];
  __shared__ __align__(16) ushort_t Bs[64 * 32];

  floatx4 acc[2][2] = {};

  const int ar = tid >> 2, ac = (tid & 3) * 8;
  const int bkk = tid >> 3, bj = (tid & 7) * 8;

  for (int k0 = 0; k0 < 256; k0 += 32) {
    uint4 av = *reinterpret_cast<const uint4*>(xc + (size_t)(mTile + ar) * 256 + k0 + ac);
    *reinterpret_cast<uint4*>(&As[ar * 32 + ac]) = av;

    uint4 bvv = *reinterpret_cast<const uint4*>(W + (size_t)(k0 + bkk) * 512 + nTile + bj);
    const ushort_t* bu = reinterpret_cast<const ushort_t*>(&bvv);
#pragma unroll
    for (int i = 0; i < 8; ++i) Bs[(bj + i) * 32 + bkk] = bu[i];
    __syncthreads();

    bf16x8 aF[2], bF[2];
#pragma unroll
    for (int mi = 0; mi < 2; ++mi)
      aF[mi] = *reinterpret_cast<const bf16x8*>(&As[(waveM * 32 + mi * 16 + l16) * 32 + quad * 8]);
#pragma unroll
    for (int ni = 0; ni < 2; ++ni)
      bF[ni] = *reinterpret_cast<const bf16x8*>(&Bs[(waveN * 32 + ni * 16 + l16) * 32 + quad * 8]);
#pragma unroll
    for (int mi = 0; mi < 2; ++mi)
#pragma unroll
      for (int ni = 0; ni < 2; ++ni)
        acc[mi][ni] = __builtin_amdgcn_mfma_f32_16x16x32_bf16(aF[mi], bF[ni], acc[mi][ni], 0, 0, 0);
    __syncthreads();
  }

#pragma unroll
  for (int mi = 0; mi < 2; ++mi) {
#pragma unroll
    for (int ni = 0; ni < 2; ++ni) {
      const int col = nTile + waveN * 32 + ni * 16 + l16;
      const float bf = bf2f(bias[col]);
#pragma unroll
      for (int r = 0; r < 4; ++r) {
        const int row = mTile + waveM * 32 + mi * 16 + quad * 4 + r;
        out[(size_t)row * 512 + col] = f2bf(acc[mi][ni][r] + bf);
      }
    }
  }
}

// ---------------------------------------------------------------------------
// K3: pooling (seeds -> rpk, rvT). Verbatim verified scalar code from the old
// k_fine pooling phases (CHK3-verified). Block = (k, h); wave wv = seed m.
// ---------------------------------------------------------------------------
__global__ __launch_bounds__(256) void k_pool(
    const ushort_t* __restrict__ Kb, const ushort_t* __restrict__ Vb,
    const int* __restrict__ pidx_all, const ushort_t* __restrict__ wc,
    ushort_t* __restrict__ rpk, ushort_t* __restrict__ rvT)
{
  const int k = blockIdx.x, h = blockIdx.y;
  const int tid = threadIdx.x, lane = tid & 63, wv = tid >> 6;
  const int* pidx = pidx_all + k * 256;

  __shared__ __align__(16) ushort_t SB[128 * 256];   // 64 KiB
  const uint32* SBU = reinterpret_cast<const uint32*>(SB);

  // stage K transposed + XOR-swizzled (verified layout)
#pragma unroll
  for (int i = 0; i < 16; ++i) {
    const int e8 = tid + 256 * i;
    const int q = e8 >> 4, dc = (e8 & 15) * 8;
    uint4 kv = *reinterpret_cast<const uint4*>(Kb + (size_t)pidx[q] * 512 + h * 128 + dc);
    const ushort_t* ku = reinterpret_cast<const ushort_t*>(&kv);
    const int qp = q >> 1, qb = q & 1;
#pragma unroll
    for (int j = 0; j < 8; ++j) {
      const int d = dc + j;
      SB[d * 256 + (((qp ^ (d & 31)) << 1) | qb)] = ku[j];
    }
  }
  __syncthreads();

  // pool softmax for seed m = wv
  float q00, q01, q10, q11;
  {
    const uint32* ssrc = reinterpret_cast<const uint32*>(wc + WC_SEED + (size_t)(wv * 4 + h) * 128);
    float s00 = 0.f, s01 = 0.f, s10 = 0.f, s11 = 0.f;
#pragma unroll 8
    for (int dc = 0; dc < 64; ++dc) {
      const uint32 qv = ssrc[dc];
      const float a0 = bflo(qv), a1 = bfhi(qv);
      const int d0 = dc * 2, d1 = d0 + 1;
      const int c0 = lane ^ (d0 & 31);
      const int c1 = lane ^ (d1 & 31);
      const uint32 u00 = SBU[d0 * 128 + c0];
      const uint32 u01 = SBU[d0 * 128 + c0 + 64];
      const uint32 u10 = SBU[d1 * 128 + c1];
      const uint32 u11 = SBU[d1 * 128 + c1 + 64];
      s00 += a0 * bflo(u00) + a1 * bflo(u10);
      s01 += a0 * bfhi(u00) + a1 * bfhi(u10);
      s10 += a0 * bflo(u01) + a1 * bflo(u11);
      s11 += a0 * bfhi(u01) + a1 * bfhi(u11);
    }
    s00 *= INV_SCALE; s01 *= INV_SCALE; s10 *= INV_SCALE; s11 *= INV_SCALE;
    float mx = fmaxf(fmaxf(s00, s01), fmaxf(s10, s11));
#pragma unroll
    for (int off = 32; off >= 1; off >>= 1) mx = fmaxf(mx, __shfl_xor(mx, off));
    const float e00 = __expf(s00 - mx), e01 = __expf(s01 - mx);
    const float e10 = __expf(s10 - mx), e11 = __expf(s11 - mx);
    float sm = e00 + e01 + e10 + e11;
#pragma unroll
    for (int off = 32; off >= 1; off >>= 1) sm += __shfl_xor(sm, off);
    const float inv = 1.0f / sm;
    q00 = e00 * inv; q01 = e01 * inv; q10 = e10 * inv; q11 = e11 * inv;
  }

  // reps_k (dims 2*lane, 2*lane+1) — verified
  {
    float rk0 = 0.f, rk1 = 0.f;
    const int d0 = 2 * lane, d1 = 2 * lane + 1;
#pragma unroll 4
    for (int qp = 0; qp < 64; ++qp) {
      const float pa = __shfl(q00, qp), pb = __shfl(q01, qp);
      const float pc = __shfl(q10, qp), pd = __shfl(q11, qp);
      const int c0 = qp ^ (d0 & 31);
      const int c1 = qp ^ (d1 & 31);
      const uint32 u0  = SBU[d0 * 128 + c0];
      const uint32 u0b = SBU[d0 * 128 + c0 + 64];
      const uint32 u1  = SBU[d1 * 128 + c1];
      const uint32 u1b = SBU[d1 * 128 + c1 + 64];
      rk0 += pa * bflo(u0) + pb * bfhi(u0) + pc * bflo(u0b) + pd * bfhi(u0b);
      rk1 += pa * bflo(u1) + pb * bfhi(u1) + pc * bflo(u1b) + pd * bfhi(u1b);
    }
    reinterpret_cast<uint32*>(rpk + ((size_t)((k * 4 + wv) * 4 + h)) * 128)[lane] = pack2bf(rk0, rk1);
  }
  __syncthreads();

  // stage V row-major and compute reps_v -> rvT (verified)
#pragma unroll
  for (int i = 0; i < 16; ++i) {
    const int e8 = tid + 256 * i;
    const int q = e8 >> 4, dc = (e8 & 15) * 8;
    uint4 vv = *reinterpret_cast<const uint4*>(Vb + (size_t)pidx[q] * 512 + h * 128 + dc);
    *reinterpret_cast<uint4*>(&SB[q * 128 + dc]) = vv;
  }
  __syncthreads();

  {
    float rv0 = 0.f, rv1 = 0.f;
#pragma unroll 4
    for (int qp = 0; qp < 64; ++qp) {
      const float pa = __shfl(q00, qp), pb = __shfl(q01, qp);
      const float pc = __shfl(q10, qp), pd = __shfl(q11, qp);
      const uint32 v00 = SBU[(2 * qp) * 64 + lane];
      const uint32 v01 = SBU[(2 * qp + 1) * 64 + lane];
      const uint32 v10 = SBU[(128 + 2 * qp) * 64 + lane];
      const uint32 v11 = SBU[(129 + 2 * qp) * 64 + lane];
      rv0 += pa * bflo(v00) + pb * bflo(v01) + pc * bflo(v10) + pd * bflo(v11);
      rv1 += pa * bfhi(v00) + pb * bfhi(v01) + pc * bfhi(v10) + pd * bfhi(v11);
    }
    const int rrep = k * 4 + wv;
    rvT[(size_t)(h * 128 + 2 * lane) * 512 + rrep]     = f2bf(rv0);
    rvT[(size_t)(h * 128 + 2 * lane + 1) * 512 + rrep] = f2bf(rv1);
  }
}

// ---------------------------------------------------------------------------
// K4: MFMA fine attention. Block = (partition k, 64-query group qg), 4 waves.
// Loops h=0..3; per head loops 4 chunks of 64 keys: QK^T MFMA, online
// softmax (k_cross template), P->Ps (A-layout), V^T staged into LDS via
// XOR-swizzle (col = ((key>>3)^(d&7))<<3 | (key&7), 8-key fragments stay
// contiguous), PV MFMA. Head-mean accumulated in regs -> locS.
// LDS: Qs 17408 + SB2 17408 + Ps 9216 = 44032 B -> 3 blocks/CU.
// ---------------------------------------------------------------------------
__global__ __launch_bounds__(256) void k_fine(
    const ushort_t* __restrict__ Qb, const ushort_t* __restrict__ Kb,
    const ushort_t* __restrict__ Vb, const int* __restrict__ pidx_all,
    ushort_t* __restrict__ locS)
{
  const int k = blockIdx.x, qg = blockIdx.y;
  const int tid = threadIdx.x, lane = tid & 63, wv = tid >> 6;
  const int l16 = lane & 15, quad = lane >> 4;
  const int* pidx = pidx_all + k * 256;

  __shared__ __align__(16) ushort_t Qs[64 * 136];
  __shared__ __align__(16) ushort_t SB2[64 * 136];     // union: K chunk [64][136] / Vt [128][64]
  __shared__ __align__(16) ushort_t Ps[4][16 * 72];

  float accS[8][4];
#pragma unroll
  for (int nt = 0; nt < 8; ++nt)
#pragma unroll
    for (int r = 0; r < 4; ++r) accS[nt][r] = 0.f;

  for (int h = 0; h < 4; ++h) {
    __syncthreads();   // prev head's Qs readers done
    // stage Q tile [64][128] -> Qs[64][136]
#pragma unroll
    for (int i = 0; i < 4; ++i) {
      const int e = tid + 256 * i;
      const int r = e >> 4, c8 = (e & 15) * 8;
      uint4 v = *reinterpret_cast<const uint4*>(Qb + (size_t)pidx[qg * 64 + r] * 512 + h * 128 + c8);
      *reinterpret_cast<uint4*>(&Qs[r * 136 + c8]) = v;
    }

    floatx4 O[8] = {};
    float m_i[4], l_i[4];
#pragma unroll
    for (int r = 0; r < 4; ++r) { m_i[r] = -3e38f; l_i[r] = 0.f; }

    for (int c = 0; c < 4; ++c) {
      __syncthreads();   // Qs visible; prev chunk's SB2 readers done
      // stage K chunk [64][128] -> SB2[64][136]
#pragma unroll
      for (int i = 0; i < 4; ++i) {
        const int e = tid + 256 * i;
        const int r = e >> 4, c8 = (e & 15) * 8;
        uint4 v = *reinterpret_cast<const uint4*>(Kb + (size_t)pidx[c * 64 + r] * 512 + h * 128 + c8);
        *reinterpret_cast<uint4*>(&SB2[r * 136 + c8]) = v;
      }
      __syncthreads();

      // scores S[16 q x 64 keys] per wave
      floatx4 S[4] = {};
#pragma unroll
      for (int ks = 0; ks < 4; ++ks) {
        bf16x8 a = *reinterpret_cast<const bf16x8*>(&Qs[(wv * 16 + l16) * 136 + ks * 32 + quad * 8]);
#pragma unroll
        for (int nt = 0; nt < 4; ++nt) {
          bf16x8 b = *reinterpret_cast<const bf16x8*>(&SB2[(nt * 16 + l16) * 136 + ks * 32 + quad * 8]);
          S[nt] = __builtin_amdgcn_mfma_f32_16x16x32_bf16(a, b, S[nt], 0, 0, 0);
        }
      }
#pragma unroll
      for (int nt = 0; nt < 4; ++nt)
#pragma unroll
        for (int r = 0; r < 4; ++r) S[nt][r] *= INV_SCALE;

      // online softmax (verified k_cross template)
#pragma unroll
      for (int r = 0; r < 4; ++r) {
        float cm = fmaxf(fmaxf(S[0][r], S[1][r]), fmaxf(S[2][r], S[3][r]));
#pragma unroll
        for (int off = 1; off <= 8; off <<= 1) cm = fmaxf(cm, __shfl_xor(cm, off));
        const float mn = fmaxf(m_i[r], cm);
        const float sc = __expf(m_i[r] - mn);
        m_i[r] = mn;
        l_i[r] *= sc;
#pragma unroll
        for (int nt = 0; nt < 8; ++nt) O[nt][r] *= sc;
        float ps = 0.f;
#pragma unroll
        for (int nt = 0; nt < 4; ++nt) {
          const float p = __expf(S[nt][r] - mn);
          ps += p;
          Ps[wv][(quad * 4 + r) * 72 + nt * 16 + l16] = f2bf(p);
        }
#pragma unroll
        for (int off = 1; off <= 8; off <<= 1) ps += __shfl_xor(ps, off);
        l_i[r] += ps;
      }
      __syncthreads();   // K reads done; Ps visible

      // stage V chunk transposed: Vt[d][64], col swizzled
#pragma unroll
      for (int i = 0; i < 4; ++i) {
        const int e = tid + 256 * i;
        const int key = e & 63, dc8 = (e >> 6) * 8;
        uint4 vv = *reinterpret_cast<const uint4*>(Vb + (size_t)pidx[c * 64 + key] * 512 + h * 128 + dc8);
        const ushort_t* u = reinterpret_cast<const ushort_t*>(&vv);
#pragma unroll
        for (int j = 0; j < 8; ++j) {
          const int d = dc8 + j;
          SB2[d * 64 + (((key >> 3) ^ j) << 3) + (key & 7)] = u[j];
        }
      }
      __syncthreads();

      // PV: O[16 x 128] += P[16 x 64] * V[64 x 128]
#pragma unroll
      for (int ks = 0; ks < 2; ++ks) {
        bf16x8 a = *reinterpret_cast<const bf16x8*>(&Ps[wv][l16 * 72 + ks * 32 + quad * 8]);
#pragma unroll
        for (int nt = 0; nt < 8; ++nt) {
          const int d = nt * 16 + l16;
          const int q8 = ks * 4 + quad;
          bf16x8 b = *reinterpret_cast<const bf16x8*>(&SB2[d * 64 + ((q8 ^ (d & 7)) << 3)]);
          O[nt] = __builtin_amdgcn_mfma_f32_16x16x32_bf16(a, b, O[nt], 0, 0, 0);
        }
      }
    }

    // accumulate head contribution
#pragma unroll
    for (int r = 0; r < 4; ++r) {
      const float inv = 1.0f / l_i[r];
#pragma unroll
      for (int nt = 0; nt < 8; ++nt) accS[nt][r] += O[nt][r] * inv;
    }
  }

  // write head-averaged local output
#pragma unroll
  for (int r = 0; r < 4; ++r) {
    const int n = pidx[qg * 64 + wv * 16 + quad * 4 + r];
#pragma unroll
    for (int nt = 0; nt < 8; ++nt)
      locS[(size_t)n * 128 + nt * 16 + l16] = f2bf(accS[nt][r] * 0.25f);
  }
}

// ---------------------------------------------------------------------------
// K5: MFMA cross-attention (verified round 7).
// ---------------------------------------------------------------------------
__global__ __launch_bounds__(256) void k_cross(
    const ushort_t* __restrict__ Qb, const ushort_t* __restrict__ rpk,
    const ushort_t* __restrict__ rvT, ushort_t* __restrict__ glb)
{
  const int h = blockIdx.y;
  const int n0 = blockIdx.x * 64;
  const int tid = threadIdx.x, lane = tid & 63, wv = tid >> 6;
  const int l16 = lane & 15, quad = lane >> 4;

  __shared__ __align__(16) ushort_t Qs[64 * 136];
  __shared__ __align__(16) ushort_t Bs[128 * 72];
  __shared__ __align__(16) ushort_t Ps[4][16 * 72];

#pragma unroll
  for (int i = 0; i < 4; ++i) {
    const int e = tid + 256 * i;
    const int r = e >> 4, c8 = (e & 15) * 8;
    uint4 v = *reinterpret_cast<const uint4*>(Qb + (size_t)(n0 + r) * 512 + h * 128 + c8);
    *reinterpret_cast<uint4*>(&Qs[r * 136 + c8]) = v;
  }

  floatx4 O[8] = {};
  float m_i[4], l_i[4];
#pragma unroll
  for (int r = 0; r < 4; ++r) { m_i[r] = -3e38f; l_i[r] = 0.f; }

  for (int c = 0; c < 8; ++c) {
    __syncthreads();
#pragma unroll
    for (int i = 0; i < 4; ++i) {
      const int e = tid + 256 * i;
      const int r = e >> 4, c8 = (e & 15) * 8;
      uint4 v = *reinterpret_cast<const uint4*>(rpk + ((size_t)((c * 64 + r) * 4 + h)) * 128 + c8);
      *reinterpret_cast<uint4*>(&Bs[r * 136 + c8]) = v;
    }
    __syncthreads();

    floatx4 S[4] = {};
#pragma unroll
    for (int ks = 0; ks < 4; ++ks) {
      bf16x8 a = *reinterpret_cast<const bf16x8*>(&Qs[(wv * 16 + l16) * 136 + ks * 32 + quad * 8]);
#pragma unroll
      for (int nt = 0; nt < 4; ++nt) {
        bf16x8 b = *reinterpret_cast<const bf16x8*>(&Bs[(nt * 16 + l16) * 136 + ks * 32 + quad * 8]);
        S[nt] = __builtin_amdgcn_mfma_f32_16x16x32_bf16(a, b, S[nt], 0, 0, 0);
      }
    }
#pragma unroll
    for (int nt = 0; nt < 4; ++nt)
#pragma unroll
      for (int r = 0; r < 4; ++r) S[nt][r] *= INV_SCALE;

#pragma unroll
    for (int r = 0; r < 4; ++r) {
      float cm = fmaxf(fmaxf(S[0][r], S[1][r]), fmaxf(S[2][r], S[3][r]));
#pragma unroll
      for (int off = 1; off <= 8; off <<= 1) cm = fmaxf(cm, __shfl_xor(cm, off));
      const float mn = fmaxf(m_i[r], cm);
      const float sc = __expf(m_i[r] - mn);
      m_i[r] = mn;
      l_i[r] *= sc;
#pragma unroll
      for (int nt = 0; nt < 8; ++nt) O[nt][r] *= sc;
      float ps = 0.f;
#pragma unroll
      for (int nt = 0; nt < 4; ++nt) {
        const float p = __expf(S[nt][r] - mn);
        ps += p;
        Ps[wv][(quad * 4 + r) * 72 + nt * 16 + l16] = f2bf(p);
      }
#pragma unroll
      for (int off = 1; off <= 8; off <<= 1) ps += __shfl_xor(ps, off);
      l_i[r] += ps;
    }
    __syncthreads();

#pragma unroll
    for (int i = 0; i < 4; ++i) {
      const int e = tid + 256 * i;
      const int d = e >> 3, c8 = (e & 7) * 8;
      uint4 v = *reinterpret_cast<const uint4*>(rvT + ((size_t)(h * 128 + d)) * 512 + c * 64 + c8);
      *reinterpret_cast<uint4*>(&Bs[d * 72 + c8]) = v;
    }
    __syncthreads();

#pragma unroll
    for (int ks = 0; ks < 2; ++ks) {
      bf16x8 a = *reinterpret_cast<const bf16x8*>(&Ps[wv][l16 * 72 + ks * 32 + quad * 8]);
#pragma unroll
      for (int nt = 0; nt < 8; ++nt) {
        bf16x8 b = *reinterpret_cast<const bf16x8*>(&Bs[(nt * 16 + l16) * 72 + ks * 32 + quad * 8]);
        O[nt] = __builtin_amdgcn_mfma_f32_16x16x32_bf16(a, b, O[nt], 0, 0, 0);
      }
    }
  }

#pragma unroll
  for (int r = 0; r < 4; ++r) {
    const float inv = 1.0f / l_i[r];
    const int n = n0 + wv * 16 + quad * 4 + r;
#pragma unroll
    for (int nt = 0; nt < 8; ++nt)
      glb[(size_t)n * 512 + h * 128 + nt * 16 + l16] = f2bf(O[nt][r] * inv);
  }
}

// ---------------------------------------------------------------------------
// K6: combine -> f32 output.
// ---------------------------------------------------------------------------
__global__ __launch_bounds__(256) void k_combine(
    const ushort_t* __restrict__ locS, const ushort_t* __restrict__ glb,
    const ushort_t* __restrict__ Vb, const float* __restrict__ scal,
    float* __restrict__ out)
{
  const int t = blockIdx.x * 256 + threadIdx.x;
  const int n = t >> 6, dp = t & 63;
  const float alpha = 1.0f / (1.0f + __expf(-scal[0]));
  const float beta = scal[1];
  const uint32 lv = reinterpret_cast<const uint32*>(locS)[(size_t)n * 64 + dp];
  float g0 = 0.f, g1 = 0.f, v0 = 0.f, v1 = 0.f;
#pragma unroll
  for (int hh = 0; hh < 4; ++hh) {
    const uint32 gv = *reinterpret_cast<const uint32*>(glb + (size_t)n * 512 + hh * 128 + 2 * dp);
    const uint32 vv = *reinterpret_cast<const uint32*>(Vb + (size_t)n * 512 + hh * 128 + 2 * dp);
    g0 += bflo(gv); g1 += bfhi(gv);
    v0 += bflo(vv); v1 += bfhi(vv);
  }
  const float r0 = alpha * bflo(lv) + (1.0f - alpha) * g0 * 0.25f + beta * v0 * 0.25f;
  const float r1 = alpha * bfhi(lv) + (1.0f - alpha) * g1 * 0.25f + beta * v1 * 0.25f;
  reinterpret_cast<float2*>(out)[(size_t)n * 64 + dp] = make_float2(r0, r1);
}

extern "C" void kernel_launch(void* const* d_in, const int* in_sizes, int n_in,
                              void* d_out, int out_size, void* d_ws, size_t ws_size,
                              hipStream_t stream) {
  const void* x     = d_in[0];
  const int*  pidx  = (const int*)d_in[1];
  const void* Wq    = d_in[2];
  const void* bq    = d_in[3];
  const void* Wk    = d_in[4];
  const void* bk    = d_in[5];
  const void* Wv    = d_in[6];
  const void* bv    = d_in[7];
  const void* seeds = d_in[8];
  const void* al    = d_in[9];
  const void* be    = d_in[10];

  char* ws = (char*)d_ws;
  ushort_t* Qb   = (ushort_t*)(ws + OFF_Q);
  ushort_t* Kb   = (ushort_t*)(ws + OFF_K);
  ushort_t* Vb   = (ushort_t*)(ws + OFF_V);
  ushort_t* locS = (ushort_t*)(ws + OFF_LOC);
  ushort_t* rpk  = (ushort_t*)(ws + OFF_RPK);
  ushort_t* xc   = (ushort_t*)(ws + OFF_XC);
  ushort_t* wc   = (ushort_t*)(ws + OFF_WC);
  float*    scal = (float*)   (ws + OFF_SCAL);
  uint32*   flags= (uint32*)  (ws + OFF_FLAG);
  ushort_t* rvT  = (ushort_t*)(ws + OFF_RVT);
  ushort_t* glb  = (ushort_t*)(ws + OFF_GLB);

  k_detect<<<1, 64, 0, stream>>>((const uint32*)x, (const ushort_t*)be, flags);
  k_convert<<<dim3(4096, 2), 256, 0, stream>>>(x, Wq, bq, Wk, bk, Wv, bv, seeds, al, be,
                                               xc, wc, scal, flags);
  k_qkv<<<dim3(8, 512, 3), 256, 0, stream>>>(xc, wc, Qb, Kb, Vb);
  k_pool<<<dim3(128, 4), 256, 0, stream>>>(Kb, Vb, pidx, wc, rpk, rvT);
  k_fine<<<dim3(128, 4), 256, 0, stream>>>(Qb, Kb, Vb, pidx, locS);
  k_cross<<<dim3(512, 4), 256, 0, stream>>>(Qb, rpk, rvT, glb);
  k_combine<<<8192, 256, 0, stream>>>(locS, glb, Vb, scal, (float*)d_out);
}

// Round 9
// 380.405 us; speedup vs baseline: 8.7404x; 1.1482x over previous
//
#include <hip/hip_runtime.h>
#include <hip/hip_bf16.h>

// PCGTConvLayer round 9: fused-QKV GEMM (x staged once/block, W^T staged via
// coalesced uint4 + XOR-swizzled LDS, conflict-free). k_convert now writes
// W^T. All other kernels verbatim from round 8 (verified).
// N=32768 IN=256 D=128 H=4 M=4 KP=128 S=256, SCALE=sqrt(128).

#define INV_SCALE 0.08838834764831845f

typedef __attribute__((ext_vector_type(8))) short bf16x8;
typedef __attribute__((ext_vector_type(4))) float floatx4;
typedef unsigned short ushort_t;
typedef unsigned int uint32;

// ---- ws layout (bytes) ----
#define OFF_Q    0ull            // bf16 [32768][512]
#define OFF_K    33554432ull     // bf16 [32768][512]
#define OFF_V    67108864ull     // bf16 [32768][512]
#define OFF_LOC  100663296ull    // bf16 [32768][128]
#define OFF_RPK  109051904ull    // bf16 [512][4][128]
#define OFF_XC   110100480ull    // bf16 [32768][256]
#define OFF_WC   126877696ull    // bf16: WqT,WkT,WvT ([512][256] each), biases, seeds
#define OFF_SCAL 127671296ull    // f32 [2]
#define OFF_FLAG 127671304ull    // u32 [2]
#define OFF_RVT  127672320ull    // bf16 [4][128][512]
#define OFF_GLB  128196608ull    // bf16 [32768][512]

#define WC_WQ 0
#define WC_WK 131072
#define WC_WV 262144
#define WC_BQ 393216
#define WC_BK 393728
#define WC_BV 394240
#define WC_SEED 394752
#define WC_TOT 396800

static __device__ __forceinline__ float bflo(uint32 u) {
  return __uint_as_float(u << 16);
}
static __device__ __forceinline__ float bfhi(uint32 u) {
  return __uint_as_float(u & 0xffff0000u);
}
static __device__ __forceinline__ float bf2f(ushort_t u) {
  return __uint_as_float(((uint32)u) << 16);
}
static __device__ __forceinline__ ushort_t f2bf(float f) {
  uint32 x = __float_as_uint(f);
  uint32 r = x + 0x7fffu + ((x >> 16) & 1u);
  return (ushort_t)(r >> 16);
}
static __device__ __forceinline__ uint32 pack2bf(float a, float b) {
  return (uint32)f2bf(a) | ((uint32)f2bf(b) << 16);
}

// ---------------------------------------------------------------------------
__global__ __launch_bounds__(64) void k_detect(const uint32* __restrict__ xw,
                                               const ushort_t* __restrict__ betaRaw,
                                               uint32* __restrict__ flags) {
  const int lane = threadIdx.x;
  const uint32 w = xw[lane * 137 + 3];
  const int e = (w >> 7) & 0xff;
  const unsigned long long b = __ballot(e >= 100 && e <= 140);
  if (lane == 0) {
    flags[0] = (__popcll(b) >= 48) ? 1u : 0u;
    flags[1] = (betaRaw[0] != 0) ? 1u : 0u;
  }
}

// ---------------------------------------------------------------------------
// K1: canonicalize. x -> xc (identity layout). W matrices -> TRANSPOSED
// bf16 [512][256] at same wc offsets. biases/seeds identity.
// ---------------------------------------------------------------------------
static __device__ __forceinline__ void conv8(const void* src, long j, int isB,
                                             ushort_t* dst) {
  if (isB) {
    *reinterpret_cast<uint4*>(dst) =
        *reinterpret_cast<const uint4*>(reinterpret_cast<const ushort_t*>(src) + j);
  } else {
    const float* f = reinterpret_cast<const float*>(src) + j;
    const float4 a = *reinterpret_cast<const float4*>(f);
    const float4 b = *reinterpret_cast<const float4*>(f + 4);
    uint4 o;
    o.x = pack2bf(a.x, a.y); o.y = pack2bf(a.z, a.w);
    o.z = pack2bf(b.x, b.y); o.w = pack2bf(b.z, b.w);
    *reinterpret_cast<uint4*>(dst) = o;
  }
}

__global__ __launch_bounds__(256) void k_convert(
    const void* __restrict__ x,
    const void* __restrict__ Wq, const void* __restrict__ bq,
    const void* __restrict__ Wk, const void* __restrict__ bk,
    const void* __restrict__ Wv, const void* __restrict__ bv,
    const void* __restrict__ seeds, const void* __restrict__ alpha,
    const void* __restrict__ beta,
    ushort_t* __restrict__ xc, ushort_t* __restrict__ wc,
    float* __restrict__ scal, const uint32* __restrict__ flags)
{
  const int isB = (int)flags[0];
  const long i8 = ((long)blockIdx.x * 256 + threadIdx.x) * 8;
  if (blockIdx.y == 0) {
    conv8(x, i8, isB, xc + i8);
  } else {
    if (i8 < WC_BQ) {
      // W region: transpose. i8 = sel*131072 + k*512 + n (8 consecutive n).
      const int sel = (int)(i8 >> 17);
      const long local = i8 & 131071;
      const int kk = (int)(local >> 9);
      const int nn = (int)(local & 511);
      const void* src = sel == 0 ? Wq : (sel == 1 ? Wk : Wv);
      ushort_t* dstW = wc + sel * 131072;
#pragma unroll
      for (int j = 0; j < 8; ++j) {
        ushort_t v;
        if (isB) v = reinterpret_cast<const ushort_t*>(src)[local + j];
        else     v = f2bf(reinterpret_cast<const float*>(src)[local + j]);
        dstW[(size_t)(nn + j) * 256 + kk] = v;
      }
    } else if (i8 < WC_TOT) {
      const void* src; long j;
      if (i8 < WC_BK)        { src = bq;    j = i8 - WC_BQ; }
      else if (i8 < WC_BV)   { src = bk;    j = i8 - WC_BK; }
      else if (i8 < WC_SEED) { src = bv;    j = i8 - WC_BV; }
      else                   { src = seeds; j = i8 - WC_SEED; }
      conv8(src, j, isB, wc + i8);
    }
    if (blockIdx.x == 0 && threadIdx.x == 0) {
      const int isBS = (int)flags[1];
      scal[0] = isBS ? bf2f(reinterpret_cast<const ushort_t*>(alpha)[0])
                     : reinterpret_cast<const float*>(alpha)[0];
      scal[1] = isBS ? bf2f(reinterpret_cast<const ushort_t*>(beta)[0])
                     : reinterpret_cast<const float*>(beta)[0];
    }
  }
}

// ---------------------------------------------------------------------------
// K2: fused QKV GEMM. One block = 64 rows of x; loops sel(3) x 8 col-chunks.
// Xs staged ONCE (XOR-swizzled: chunk c of row at ((c^(row&7))<<3)); Ws from
// W^T with identical swizzle via coalesced uint4. MFMA 16x16x32, wave =
// 16 rows x 64 cols per chunk. LDS exactly 64 KiB.
// ---------------------------------------------------------------------------
__global__ __launch_bounds__(256) void k_qkv(
    const ushort_t* __restrict__ xc, const ushort_t* __restrict__ wc,
    ushort_t* __restrict__ Qb, ushort_t* __restrict__ Kb, ushort_t* __restrict__ Vb)
{
  const int m0 = blockIdx.x * 64;
  const int tid = threadIdx.x, lane = tid & 63, wv = tid >> 6;
  const int l16 = lane & 15, quad = lane >> 4;

  __shared__ __align__(16) ushort_t Xs[64 * 256];   // 32 KiB
  __shared__ __align__(16) ushort_t Ws[64 * 256];   // 32 KiB

#pragma unroll
  for (int i = 0; i < 8; ++i) {
    const int id = tid + 256 * i;          // 2048 chunks of 8
    const int row = id >> 5, c = id & 31;
    uint4 v = *reinterpret_cast<const uint4*>(xc + (size_t)(m0 + row) * 256 + c * 8);
    *reinterpret_cast<uint4*>(&Xs[row * 256 + ((c ^ (row & 7)) << 3)]) = v;
  }

  for (int sel = 0; sel < 3; ++sel) {
    const ushort_t* WT   = wc + sel * 131072;
    const ushort_t* bias = wc + WC_BQ + sel * 512;
    ushort_t* out        = sel == 0 ? Qb : (sel == 1 ? Kb : Vb);
    for (int nc = 0; nc < 8; ++nc) {
      const int n0 = nc * 64;
      __syncthreads();   // prev chunk's Ws readers done (also orders Xs staging)
#pragma unroll
      for (int i = 0; i < 8; ++i) {
        const int id = tid + 256 * i;
        const int row = id >> 5, c = id & 31;
        uint4 v = *reinterpret_cast<const uint4*>(WT + (size_t)(n0 + row) * 256 + c * 8);
        *reinterpret_cast<uint4*>(&Ws[row * 256 + ((c ^ (row & 7)) << 3)]) = v;
      }
      __syncthreads();

      floatx4 acc[4] = {};
      const int arow = wv * 16 + l16;
#pragma unroll
      for (int ks = 0; ks < 8; ++ks) {
        const int ac = ks * 4 + quad;
        bf16x8 a = *reinterpret_cast<const bf16x8*>(&Xs[arow * 256 + ((ac ^ (arow & 7)) << 3)]);
#pragma unroll
        for (int nt = 0; nt < 4; ++nt) {
          const int brow = nt * 16 + l16;
          bf16x8 b = *reinterpret_cast<const bf16x8*>(&Ws[brow * 256 + ((ac ^ (brow & 7)) << 3)]);
          acc[nt] = __builtin_amdgcn_mfma_f32_16x16x32_bf16(a, b, acc[nt], 0, 0, 0);
        }
      }

#pragma unroll
      for (int nt = 0; nt < 4; ++nt) {
        const int col = n0 + nt * 16 + l16;
        const float bf = bf2f(bias[col]);
#pragma unroll
        for (int r = 0; r < 4; ++r) {
          const int row = m0 + wv * 16 + quad * 4 + r;
          out[(size_t)row * 512 + col] = f2bf(acc[nt][r] + bf);
        }
      }
    }
  }
}

// ---------------------------------------------------------------------------
// K3: pooling (seeds -> rpk, rvT). Verified (CHK3).
// ---------------------------------------------------------------------------
__global__ __launch_bounds__(256) void k_pool(
    const ushort_t* __restrict__ Kb, const ushort_t* __restrict__ Vb,
    const int* __restrict__ pidx_all, const ushort_t* __restrict__ wc,
    ushort_t* __restrict__ rpk, ushort_t* __restrict__ rvT)
{
  const int k = blockIdx.x, h = blockIdx.y;
  const int tid = threadIdx.x, lane = tid & 63, wv = tid >> 6;
  const int* pidx = pidx_all + k * 256;

  __shared__ __align__(16) ushort_t SB[128 * 256];
  const uint32* SBU = reinterpret_cast<const uint32*>(SB);

#pragma unroll
  for (int i = 0; i < 16; ++i) {
    const int e8 = tid + 256 * i;
    const int q = e8 >> 4, dc = (e8 & 15) * 8;
    uint4 kv = *reinterpret_cast<const uint4*>(Kb + (size_t)pidx[q] * 512 + h * 128 + dc);
    const ushort_t* ku = reinterpret_cast<const ushort_t*>(&kv);
    const int qp = q >> 1, qb = q & 1;
#pragma unroll
    for (int j = 0; j < 8; ++j) {
      const int d = dc + j;
      SB[d * 256 + (((qp ^ (d & 31)) << 1) | qb)] = ku[j];
    }
  }
  __syncthreads();

  float q00, q01, q10, q11;
  {
    const uint32* ssrc = reinterpret_cast<const uint32*>(wc + WC_SEED + (size_t)(wv * 4 + h) * 128);
    float s00 = 0.f, s01 = 0.f, s10 = 0.f, s11 = 0.f;
#pragma unroll 8
    for (int dc = 0; dc < 64; ++dc) {
      const uint32 qv = ssrc[dc];
      const float a0 = bflo(qv), a1 = bfhi(qv);
      const int d0 = dc * 2, d1 = d0 + 1;
      const int c0 = lane ^ (d0 & 31);
      const int c1 = lane ^ (d1 & 31);
      const uint32 u00 = SBU[d0 * 128 + c0];
      const uint32 u01 = SBU[d0 * 128 + c0 + 64];
      const uint32 u10 = SBU[d1 * 128 + c1];
      const uint32 u11 = SBU[d1 * 128 + c1 + 64];
      s00 += a0 * bflo(u00) + a1 * bflo(u10);
      s01 += a0 * bfhi(u00) + a1 * bfhi(u10);
      s10 += a0 * bflo(u01) + a1 * bflo(u11);
      s11 += a0 * bfhi(u01) + a1 * bfhi(u11);
    }
    s00 *= INV_SCALE; s01 *= INV_SCALE; s10 *= INV_SCALE; s11 *= INV_SCALE;
    float mx = fmaxf(fmaxf(s00, s01), fmaxf(s10, s11));
#pragma unroll
    for (int off = 32; off >= 1; off >>= 1) mx = fmaxf(mx, __shfl_xor(mx, off));
    const float e00 = __expf(s00 - mx), e01 = __expf(s01 - mx);
    const float e10 = __expf(s10 - mx), e11 = __expf(s11 - mx);
    float sm = e00 + e01 + e10 + e11;
#pragma unroll
    for (int off = 32; off >= 1; off >>= 1) sm += __shfl_xor(sm, off);
    const float inv = 1.0f / sm;
    q00 = e00 * inv; q01 = e01 * inv; q10 = e10 * inv; q11 = e11 * inv;
  }

  {
    float rk0 = 0.f, rk1 = 0.f;
    const int d0 = 2 * lane, d1 = 2 * lane + 1;
#pragma unroll 4
    for (int qp = 0; qp < 64; ++qp) {
      const float pa = __shfl(q00, qp), pb = __shfl(q01, qp);
      const float pc = __shfl(q10, qp), pd = __shfl(q11, qp);
      const int c0 = qp ^ (d0 & 31);
      const int c1 = qp ^ (d1 & 31);
      const uint32 u0  = SBU[d0 * 128 + c0];
      const uint32 u0b = SBU[d0 * 128 + c0 + 64];
      const uint32 u1  = SBU[d1 * 128 + c1];
      const uint32 u1b = SBU[d1 * 128 + c1 + 64];
      rk0 += pa * bflo(u0) + pb * bfhi(u0) + pc * bflo(u0b) + pd * bfhi(u0b);
      rk1 += pa * bflo(u1) + pb * bfhi(u1) + pc * bflo(u1b) + pd * bfhi(u1b);
    }
    reinterpret_cast<uint32*>(rpk + ((size_t)((k * 4 + wv) * 4 + h)) * 128)[lane] = pack2bf(rk0, rk1);
  }
  __syncthreads();

#pragma unroll
  for (int i = 0; i < 16; ++i) {
    const int e8 = tid + 256 * i;
    const int q = e8 >> 4, dc = (e8 & 15) * 8;
    uint4 vv = *reinterpret_cast<const uint4*>(Vb + (size_t)pidx[q] * 512 + h * 128 + dc);
    *reinterpret_cast<uint4*>(&SB[q * 128 + dc]) = vv;
  }
  __syncthreads();

  {
    float rv0 = 0.f, rv1 = 0.f;
#pragma unroll 4
    for (int qp = 0; qp < 64; ++qp) {
      const float pa = __shfl(q00, qp), pb = __shfl(q01, qp);
      const float pc = __shfl(q10, qp), pd = __shfl(q11, qp);
      const uint32 v00 = SBU[(2 * qp) * 64 + lane];
      const uint32 v01 = SBU[(2 * qp + 1) * 64 + lane];
      const uint32 v10 = SBU[(128 + 2 * qp) * 64 + lane];
      const uint32 v11 = SBU[(129 + 2 * qp) * 64 + lane];
      rv0 += pa * bflo(v00) + pb * bflo(v01) + pc * bflo(v10) + pd * bflo(v11);
      rv1 += pa * bfhi(v00) + pb * bfhi(v01) + pc * bfhi(v10) + pd * bfhi(v11);
    }
    const int rrep = k * 4 + wv;
    rvT[(size_t)(h * 128 + 2 * lane) * 512 + rrep]     = f2bf(rv0);
    rvT[(size_t)(h * 128 + 2 * lane + 1) * 512 + rrep] = f2bf(rv1);
  }
}

// ---------------------------------------------------------------------------
// K4: MFMA fine attention (verified round 8).
// ---------------------------------------------------------------------------
__global__ __launch_bounds__(256) void k_fine(
    const ushort_t* __restrict__ Qb, const ushort_t* __restrict__ Kb,
    const ushort_t* __restrict__ Vb, const int* __restrict__ pidx_all,
    ushort_t* __restrict__ locS)
{
  const int k = blockIdx.x, qg = blockIdx.y;
  const int tid = threadIdx.x, lane = tid & 63, wv = tid >> 6;
  const int l16 = lane & 15, quad = lane >> 4;
  const int* pidx = pidx_all + k * 256;

  __shared__ __align__(16) ushort_t Qs[64 * 136];
  __shared__ __align__(16) ushort_t SB2[64 * 136];
  __shared__ __align__(16) ushort_t Ps[4][16 * 72];

  float accS[8][4];
#pragma unroll
  for (int nt = 0; nt < 8; ++nt)
#pragma unroll
    for (int r = 0; r < 4; ++r) accS[nt][r] = 0.f;

  for (int h = 0; h < 4; ++h) {
    __syncthreads();
#pragma unroll
    for (int i = 0; i < 4; ++i) {
      const int e = tid + 256 * i;
      const int r = e >> 4, c8 = (e & 15) * 8;
      uint4 v = *reinterpret_cast<const uint4*>(Qb + (size_t)pidx[qg * 64 + r] * 512 + h * 128 + c8);
      *reinterpret_cast<uint4*>(&Qs[r * 136 + c8]) = v;
    }

    floatx4 O[8] = {};
    float m_i[4], l_i[4];
#pragma unroll
    for (int r = 0; r < 4; ++r) { m_i[r] = -3e38f; l_i[r] = 0.f; }

    for (int c = 0; c < 4; ++c) {
      __syncthreads();
#pragma unroll
      for (int i = 0; i < 4; ++i) {
        const int e = tid + 256 * i;
        const int r = e >> 4, c8 = (e & 15) * 8;
        uint4 v = *reinterpret_cast<const uint4*>(Kb + (size_t)pidx[c * 64 + r] * 512 + h * 128 + c8);
        *reinterpret_cast<uint4*>(&SB2[r * 136 + c8]) = v;
      }
      __syncthreads();

      floatx4 S[4] = {};
#pragma unroll
      for (int ks = 0; ks < 4; ++ks) {
        bf16x8 a = *reinterpret_cast<const bf16x8*>(&Qs[(wv * 16 + l16) * 136 + ks * 32 + quad * 8]);
#pragma unroll
        for (int nt = 0; nt < 4; ++nt) {
          bf16x8 b = *reinterpret_cast<const bf16x8*>(&SB2[(nt * 16 + l16) * 136 + ks * 32 + quad * 8]);
          S[nt] = __builtin_amdgcn_mfma_f32_16x16x32_bf16(a, b, S[nt], 0, 0, 0);
        }
      }
#pragma unroll
      for (int nt = 0; nt < 4; ++nt)
#pragma unroll
        for (int r = 0; r < 4; ++r) S[nt][r] *= INV_SCALE;

#pragma unroll
      for (int r = 0; r < 4; ++r) {
        float cm = fmaxf(fmaxf(S[0][r], S[1][r]), fmaxf(S[2][r], S[3][r]));
#pragma unroll
        for (int off = 1; off <= 8; off <<= 1) cm = fmaxf(cm, __shfl_xor(cm, off));
        const float mn = fmaxf(m_i[r], cm);
        const float sc = __expf(m_i[r] - mn);
        m_i[r] = mn;
        l_i[r] *= sc;
#pragma unroll
        for (int nt = 0; nt < 8; ++nt) O[nt][r] *= sc;
        float ps = 0.f;
#pragma unroll
        for (int nt = 0; nt < 4; ++nt) {
          const float p = __expf(S[nt][r] - mn);
          ps += p;
          Ps[wv][(quad * 4 + r) * 72 + nt * 16 + l16] = f2bf(p);
        }
#pragma unroll
        for (int off = 1; off <= 8; off <<= 1) ps += __shfl_xor(ps, off);
        l_i[r] += ps;
      }
      __syncthreads();

#pragma unroll
      for (int i = 0; i < 4; ++i) {
        const int e = tid + 256 * i;
        const int key = e & 63, dc8 = (e >> 6) * 8;
        uint4 vv = *reinterpret_cast<const uint4*>(Vb + (size_t)pidx[c * 64 + key] * 512 + h * 128 + dc8);
        const ushort_t* u = reinterpret_cast<const ushort_t*>(&vv);
#pragma unroll
        for (int j = 0; j < 8; ++j) {
          const int d = dc8 + j;
          SB2[d * 64 + (((key >> 3) ^ j) << 3) + (key & 7)] = u[j];
        }
      }
      __syncthreads();

#pragma unroll
      for (int ks = 0; ks < 2; ++ks) {
        bf16x8 a = *reinterpret_cast<const bf16x8*>(&Ps[wv][l16 * 72 + ks * 32 + quad * 8]);
#pragma unroll
        for (int nt = 0; nt < 8; ++nt) {
          const int d = nt * 16 + l16;
          const int q8 = ks * 4 + quad;
          bf16x8 b = *reinterpret_cast<const bf16x8*>(&SB2[d * 64 + ((q8 ^ (d & 7)) << 3)]);
          O[nt] = __builtin_amdgcn_mfma_f32_16x16x32_bf16(a, b, O[nt], 0, 0, 0);
        }
      }
    }

#pragma unroll
    for (int r = 0; r < 4; ++r) {
      const float inv = 1.0f / l_i[r];
#pragma unroll
      for (int nt = 0; nt < 8; ++nt) accS[nt][r] += O[nt][r] * inv;
    }
  }

#pragma unroll
  for (int r = 0; r < 4; ++r) {
    const int n = pidx[qg * 64 + wv * 16 + quad * 4 + r];
#pragma unroll
    for (int nt = 0; nt < 8; ++nt)
      locS[(size_t)n * 128 + nt * 16 + l16] = f2bf(accS[nt][r] * 0.25f);
  }
}

// ---------------------------------------------------------------------------
// K5: MFMA cross-attention (verified round 7).
// ---------------------------------------------------------------------------
__global__ __launch_bounds__(256) void k_cross(
    const ushort_t* __restrict__ Qb, const ushort_t* __restrict__ rpk,
    const ushort_t* __restrict__ rvT, ushort_t* __restrict__ glb)
{
  const int h = blockIdx.y;
  const int n0 = blockIdx.x * 64;
  const int tid = threadIdx.x, lane = tid & 63, wv = tid >> 6;
  const int l16 = lane & 15, quad = lane >> 4;

  __shared__ __align__(16) ushort_t Qs[64 * 136];
  __shared__ __align__(16) ushort_t Bs[128 * 72];
  __shared__ __align__(16) ushort_t Ps[4][16 * 72];

#pragma unroll
  for (int i = 0; i < 4; ++i) {
    const int e = tid + 256 * i;
    const int r = e >> 4, c8 = (e & 15) * 8;
    uint4 v = *reinterpret_cast<const uint4*>(Qb + (size_t)(n0 + r) * 512 + h * 128 + c8);
    *reinterpret_cast<uint4*>(&Qs[r * 136 + c8]) = v;
  }

  floatx4 O[8] = {};
  float m_i[4], l_i[4];
#pragma unroll
  for (int r = 0; r < 4; ++r) { m_i[r] = -3e38f; l_i[r] = 0.f; }

  for (int c = 0; c < 8; ++c) {
    __syncthreads();
#pragma unroll
    for (int i = 0; i < 4; ++i) {
      const int e = tid + 256 * i;
      const int r = e >> 4, c8 = (e & 15) * 8;
      uint4 v = *reinterpret_cast<const uint4*>(rpk + ((size_t)((c * 64 + r) * 4 + h)) * 128 + c8);
      *reinterpret_cast<uint4*>(&Bs[r * 136 + c8]) = v;
    }
    __syncthreads();

    floatx4 S[4] = {};
#pragma unroll
    for (int ks = 0; ks < 4; ++ks) {
      bf16x8 a = *reinterpret_cast<const bf16x8*>(&Qs[(wv * 16 + l16) * 136 + ks * 32 + quad * 8]);
#pragma unroll
      for (int nt = 0; nt < 4; ++nt) {
        bf16x8 b = *reinterpret_cast<const bf16x8*>(&Bs[(nt * 16 + l16) * 136 + ks * 32 + quad * 8]);
        S[nt] = __builtin_amdgcn_mfma_f32_16x16x32_bf16(a, b, S[nt], 0, 0, 0);
      }
    }
#pragma unroll
    for (int nt = 0; nt < 4; ++nt)
#pragma unroll
      for (int r = 0; r < 4; ++r) S[nt][r] *= INV_SCALE;

#pragma unroll
    for (int r = 0; r < 4; ++r) {
      float cm = fmaxf(fmaxf(S[0][r], S[1][r]), fmaxf(S[2][r], S[3][r]));
#pragma unroll
      for (int off = 1; off <= 8; off <<= 1) cm = fmaxf(cm, __shfl_xor(cm, off));
      const float mn = fmaxf(m_i[r], cm);
      const float sc = __expf(m_i[r] - mn);
      m_i[r] = mn;
      l_i[r] *= sc;
#pragma unroll
      for (int nt = 0; nt < 8; ++nt) O[nt][r] *= sc;
      float ps = 0.f;
#pragma unroll
      for (int nt = 0; nt < 4; ++nt) {
        const float p = __expf(S[nt][r] - mn);
        ps += p;
        Ps[wv][(quad * 4 + r) * 72 + nt * 16 + l16] = f2bf(p);
      }
#pragma unroll
      for (int off = 1; off <= 8; off <<= 1) ps += __shfl_xor(ps, off);
      l_i[r] += ps;
    }
    __syncthreads();

#pragma unroll
    for (int i = 0; i < 4; ++i) {
      const int e = tid + 256 * i;
      const int d = e >> 3, c8 = (e & 7) * 8;
      uint4 v = *reinterpret_cast<const uint4*>(rvT + ((size_t)(h * 128 + d)) * 512 + c * 64 + c8);
      *reinterpret_cast<uint4*>(&Bs[d * 72 + c8]) = v;
    }
    __syncthreads();

#pragma unroll
    for (int ks = 0; ks < 2; ++ks) {
      bf16x8 a = *reinterpret_cast<const bf16x8*>(&Ps[wv][l16 * 72 + ks * 32 + quad * 8]);
#pragma unroll
      for (int nt = 0; nt < 8; ++nt) {
        bf16x8 b = *reinterpret_cast<const bf16x8*>(&Bs[(nt * 16 + l16) * 72 + ks * 32 + quad * 8]);
        O[nt] = __builtin_amdgcn_mfma_f32_16x16x32_bf16(a, b, O[nt], 0, 0, 0);
      }
    }
  }

#pragma unroll
  for (int r = 0; r < 4; ++r) {
    const float inv = 1.0f / l_i[r];
    const int n = n0 + wv * 16 + quad * 4 + r;
#pragma unroll
    for (int nt = 0; nt < 8; ++nt)
      glb[(size_t)n * 512 + h * 128 + nt * 16 + l16] = f2bf(O[nt][r] * inv);
  }
}

// ---------------------------------------------------------------------------
// K6: combine -> f32 output.
// ---------------------------------------------------------------------------
__global__ __launch_bounds__(256) void k_combine(
    const ushort_t* __restrict__ locS, const ushort_t* __restrict__ glb,
    const ushort_t* __restrict__ Vb, const float* __restrict__ scal,
    float* __restrict__ out)
{
  const int t = blockIdx.x * 256 + threadIdx.x;
  const int n = t >> 6, dp = t & 63;
  const float alpha = 1.0f / (1.0f + __expf(-scal[0]));
  const float beta = scal[1];
  const uint32 lv = reinterpret_cast<const uint32*>(locS)[(size_t)n * 64 + dp];
  float g0 = 0.f, g1 = 0.f, v0 = 0.f, v1 = 0.f;
#pragma unroll
  for (int hh = 0; hh < 4; ++hh) {
    const uint32 gv = *reinterpret_cast<const uint32*>(glb + (size_t)n * 512 + hh * 128 + 2 * dp);
    const uint32 vv = *reinterpret_cast<const uint32*>(Vb + (size_t)n * 512 + hh * 128 + 2 * dp);
    g0 += bflo(gv); g1 += bfhi(gv);
    v0 += bflo(vv); v1 += bfhi(vv);
  }
  const float r0 = alpha * bflo(lv) + (1.0f - alpha) * g0 * 0.25f + beta * v0 * 0.25f;
  const float r1 = alpha * bfhi(lv) + (1.0f - alpha) * g1 * 0.25f + beta * v1 * 0.25f;
  reinterpret_cast<float2*>(out)[(size_t)n * 64 + dp] = make_float2(r0, r1);
}

extern "C" void kernel_launch(void* const* d_in, const int* in_sizes, int n_in,
                              void* d_out, int out_size, void* d_ws, size_t ws_size,
                              hipStream_t stream) {
  const void* x     = d_in[0];
  const int*  pidx  = (const int*)d_in[1];
  const void* Wq    = d_in[2];
  const void* bq    = d_in[3];
  const void* Wk    = d_in[4];
  const void* bk    = d_in[5];
  const void* Wv    = d_in[6];
  const void* bv    = d_in[7];
  const void* seeds = d_in[8];
  const void* al    = d_in[9];
  const void* be    = d_in[10];

  char* ws = (char*)d_ws;
  ushort_t* Qb   = (ushort_t*)(ws + OFF_Q);
  ushort_t* Kb   = (ushort_t*)(ws + OFF_K);
  ushort_t* Vb   = (ushort_t*)(ws + OFF_V);
  ushort_t* locS = (ushort_t*)(ws + OFF_LOC);
  ushort_t* rpk  = (ushort_t*)(ws + OFF_RPK);
  ushort_t* xc   = (ushort_t*)(ws + OFF_XC);
  ushort_t* wc   = (ushort_t*)(ws + OFF_WC);
  float*    scal = (float*)   (ws + OFF_SCAL);
  uint32*   flags= (uint32*)  (ws + OFF_FLAG);
  ushort_t* rvT  = (ushort_t*)(ws + OFF_RVT);
  ushort_t* glb  = (ushort_t*)(ws + OFF_GLB);

  k_detect<<<1, 64, 0, stream>>>((const uint32*)x, (const ushort_t*)be, flags);
  k_convert<<<dim3(4096, 2), 256, 0, stream>>>(x, Wq, bq, Wk, bk, Wv, bv, seeds, al, be,
                                               xc, wc, scal, flags);
  k_qkv<<<512, 256, 0, stream>>>(xc, wc, Qb, Kb, Vb);
  k_pool<<<dim3(128, 4), 256, 0, stream>>>(Kb, Vb, pidx, wc, rpk, rvT);
  k_fine<<<dim3(128, 4), 256, 0, stream>>>(Qb, Kb, Vb, pidx, locS);
  k_cross<<<dim3(512, 4), 256, 0, stream>>>(Qb, rpk, rvT, glb);
  k_combine<<<8192, 256, 0, stream>>>(locS, glb, Vb, scal, (float*)d_out);
}